// Round 9
// baseline (368.826 us; speedup 1.0000x reference)
//
#include <hip/hip_runtime.h>
#include <hip/hip_bf16.h>

// FBANetLayer: Swin-style block. H=W=512, DIM=128, WL=8, SS=4, HEADS=4, HD=32.
// attn: head-per-wave; swapped-QK^T scores with bias C-init; max-free softmax;
//       wave-private LDS; residual prefetch; raw lgkm-only barriers.
// mlp:  grid 4096 x 1 tile(64 rows); w1/w2 frags streamed per hidden-chunk;
//       x1 stashed bf16 in LDS during LN2 -> epilogue is PURE WRITE (no
//       out re-read; saves 134MB HBM fetch); LDS 67KB -> 2 blocks/CU.

typedef __bf16 bf16x8 __attribute__((ext_vector_type(8)));
typedef __bf16 bf16x2 __attribute__((ext_vector_type(2)));
typedef float f32x4 __attribute__((ext_vector_type(4)));

#define MFMA16(a, b, c) __builtin_amdgcn_mfma_f32_16x16x32_bf16(a, b, c, 0, 0, 0)
#define LGKM_BARRIER() do { \
    asm volatile("s_waitcnt lgkmcnt(0)" ::: "memory"); \
    __builtin_amdgcn_s_barrier(); } while (0)

#define SS 4
#define XS 136   // attn LDS stride (bf16) for the 128-wide xn tile (2-way banks)
#define QKS 40   // stride for 32-wide q/k/O tiles (2-way banks)
#define PSS 72   // stride for 64-wide ps / vt tiles (2-way banks)
#define X1S 140  // mlp x1-stash stride: lk-groups land on disjoint bank quads

// ws byte offsets (total 458,752 B)
#define QKV_W_OFF 0        // 384x128 bf16 frag-order: ((h*6+nt)*4+kk)*512 + lane*8
#define PROJ_W_OFF 98304   // 128x128 bf16 frag-order: ((wid*2+nt2)*4+kk)*512 + lane*8
#define W1_OFF 131072      // 512x128 bf16 frag-order (chunked): (((c*8+wid)*2+nt)*4+kk)*512+lane*8
#define W2_OFF 262144      // 128x512 bf16 frag-order: (wid*16+kk)*512 + lane*8
#define BIAS_OFF 393216    // bias C-frag table: f32[((h*4+qt)*4+kt)*256 + lane*4 + i]

__device__ __forceinline__ int regid(int u) { return (u >= 508) ? 2 : ((u >= 504) ? 1 : 0); }

__global__ __launch_bounds__(256) void prep_kernel(
    const float* __restrict__ qkv_w, const float* __restrict__ proj_w,
    const float* __restrict__ w1, const float* __restrict__ w2,
    const float* __restrict__ rel_bias, unsigned char* __restrict__ ws) {
  int tid = blockIdx.x * 256 + threadIdx.x;
  __bf16* qw = (__bf16*)(ws + QKV_W_OFF);
  __bf16* pw = (__bf16*)(ws + PROJ_W_OFF);
  __bf16* w1b = (__bf16*)(ws + W1_OFF);
  __bf16* w2b = (__bf16*)(ws + W2_OFF);
  float* btbl = (float*)(ws + BIAS_OFF);
  if (tid < 49152) {
    int e = tid & 7, lane = (tid >> 3) & 63, kk = (tid >> 9) & 3;
    int f = tid >> 11;            // 0..23 = h*6+nt
    int h = f / 6, nt = f % 6;
    int j = (nt >> 1) * 128 + h * 32 + (nt & 1) * 16 + (lane & 15);
    int k = kk * 32 + (lane >> 4) * 8 + e;
    qw[tid] = (__bf16)qkv_w[j * 128 + k];
  }
  if (tid < 16384) {
    int e = tid & 7, lane = (tid >> 3) & 63, kk = (tid >> 9) & 3;
    int nt2 = (tid >> 11) & 1, wid = (tid >> 12) & 3;
    int j = wid * 32 + nt2 * 16 + (lane & 15);
    int k = kk * 32 + (lane >> 4) * 8 + e;
    pw[tid] = (__bf16)proj_w[j * 128 + k];
  }
  if (tid < 65536) {
    { // w1 chunked frag order: c,wid,nt,kk
      int e = tid & 7, lane = (tid >> 3) & 63, kk = (tid >> 9) & 3;
      int nt = (tid >> 11) & 1, wid = (tid >> 12) & 7, c = (tid >> 15) & 1;
      int j = c * 256 + wid * 32 + nt * 16 + (lane & 15);
      int k = kk * 32 + (lane >> 4) * 8 + e;
      w1b[tid] = (__bf16)w1[j * 128 + k]; }
    { int e = tid & 7, lane = (tid >> 3) & 63, kk = (tid >> 9) & 15, wid = (tid >> 13) & 7;
      int j = wid * 16 + (lane & 15);
      int k = kk * 32 + (lane >> 4) * 8 + e;
      w2b[tid] = (__bf16)w2[j * 512 + k]; }
  }
  if (tid < 16384) {
    // bias C-frag table: lane holds C[row=k-tok=(l>>4)*4+i][col=q-tok=l&15]
    int i = tid & 3, lane = (tid >> 2) & 63;
    int kt = (tid >> 8) & 3, qt = (tid >> 10) & 3, h = (tid >> 12) & 3;
    int n = qt * 16 + (lane & 15);          // q token
    int m = kt * 16 + (lane >> 4) * 4 + i;  // k token
    int idx = ((n >> 3) - (m >> 3) + 7) * 15 + ((n & 7) - (m & 7) + 7);
    btbl[tid] = rel_bias[idx * 4 + h];
  }
}

__global__ __launch_bounds__(256, 2) void attn_kernel(
    const float* __restrict__ x, const float* __restrict__ ln1_w, const float* __restrict__ ln1_b,
    const float* __restrict__ qkv_b, const float* __restrict__ proj_b,
    const unsigned char* __restrict__ ws, float* __restrict__ out) {
  __shared__ __attribute__((aligned(16))) __bf16 xn[64 * XS];   // 17,408 B
  __shared__ __attribute__((aligned(16))) __bf16 wreg[4][5120]; // 4 x 10,240 B
  __shared__ __attribute__((aligned(16))) __bf16 vt[4][32 * PSS]; // 4 x 4,608 B
  __shared__ __attribute__((aligned(16))) int rid[64];

  const int w = blockIdx.x;
  const int wi = w >> 6, wj = w & 63;
  const int tid = threadIdx.x;
  const int wid = tid >> 6, lane = tid & 63;
  const int lr = lane & 15, lk = lane >> 4;
  const bool edge = (wi == 63) || (wj == 63);
  const f32x4 zero4 = {0.f, 0.f, 0.f, 0.f};

  // ---- Hoisted QKV B-frags: wave wid's head slice {Q_h,K_h,V_h} ----
  const __bf16* qw = (const __bf16*)(ws + QKV_W_OFF);
  bf16x8 bw[6][4];
  float qb[6];
#pragma unroll
  for (int nt = 0; nt < 6; nt++) {
    qb[nt] = qkv_b[(nt >> 1) * 128 + wid * 32 + (nt & 1) * 16 + lr];
#pragma unroll
    for (int kk = 0; kk < 4; kk++)
      bw[nt][kk] = *(const bf16x8*)(qw + ((wid * 6 + nt) * 4 + kk) * 512 + lane * 8);
  }

  // ---- Phase A: gather rolled rows + LN1 -> bf16 LDS ----
  {
    int n = tid >> 2, q = tid & 3;
    int r = n >> 3, c = n & 7;
    int io = (wi * 8 + r + SS) & 511;
    int jo = (wj * 8 + c + SS) & 511;
    size_t gid = (size_t)io * 512 + jo;
    const float4* xp = (const float4*)(x + gid * 128 + q * 32);
    float4 xv[8];
    float s = 0.f, s2 = 0.f;
#pragma unroll
    for (int t = 0; t < 8; t++) {
      float4 v = xp[t]; xv[t] = v;
      s += v.x + v.y + v.z + v.w;
      s2 += v.x * v.x + v.y * v.y + v.z * v.z + v.w * v.w;
    }
    s += __shfl_xor(s, 1); s += __shfl_xor(s, 2);
    s2 += __shfl_xor(s2, 1); s2 += __shfl_xor(s2, 2);
    float mean = s * (1.f / 128.f);
    float var = s2 * (1.f / 128.f) - mean * mean;
    float rstd = rsqrtf(var + 1e-5f);
    const float4* wv = (const float4*)(ln1_w + q * 32);
    const float4* bv = (const float4*)(ln1_b + q * 32);
    __bf16* dst = xn + n * XS + q * 32;
#pragma unroll
    for (int t = 0; t < 8; t++) {
      float4 wt = wv[t], bt = bv[t], v = xv[t];
      dst[t * 4 + 0] = (__bf16)((v.x - mean) * rstd * wt.x + bt.x);
      dst[t * 4 + 1] = (__bf16)((v.y - mean) * rstd * wt.y + bt.y);
      dst[t * 4 + 2] = (__bf16)((v.z - mean) * rstd * wt.z + bt.z);
      dst[t * 4 + 3] = (__bf16)((v.w - mean) * rstd * wt.w + bt.w);
    }
    if (q == 0) rid[n] = 3 * regid(wi * 8 + r) + regid(wj * 8 + c);
  }
  LGKM_BARRIER();   // keep hoisted bw loads in flight (no vmcnt drain)

  // ---- Phase B: QKV for head wid (64 rows x 96 cols), into private LDS ----
  {
    const float scale = 0.17677669529663687f;  // 32^-0.5 folded into Q
    __bf16* qbase = &wreg[wid][0];
    __bf16* kbase = &wreg[wid][2560];
    __bf16* vbase = &vt[wid][0];
#pragma unroll
    for (int st = 0; st < 4; st++) {
      bf16x8 a[4];
#pragma unroll
      for (int kk = 0; kk < 4; kk++)
        a[kk] = *(const bf16x8*)(xn + (st * 16 + lr) * XS + kk * 32 + lk * 8);
#pragma unroll
      for (int nt = 0; nt < 6; nt++) {
        f32x4 acc = zero4;
#pragma unroll
        for (int kk = 0; kk < 4; kk++) acc = MFMA16(a[kk], bw[nt][kk], acc);
        float bias = qb[nt];
        int dl = (nt & 1) * 16 + lr;           // d_local within head
        if (nt < 2) {
#pragma unroll
          for (int i = 0; i < 4; i++)
            qbase[(st * 16 + lk * 4 + i) * QKS + dl] = (__bf16)((acc[i] + bias) * scale);
        } else if (nt < 4) {
#pragma unroll
          for (int i = 0; i < 4; i++)
            kbase[(st * 16 + lk * 4 + i) * QKS + dl] = (__bf16)(acc[i] + bias);
        } else {
#pragma unroll
          for (int i = 0; i < 4; i++)
            vbase[dl * PSS + st * 16 + lk * 4 + i] = (__bf16)(acc[i] + bias);
        }
      }
    }
  }

  // ---- hoist proj B-frags + bias C-frags (loads overlap frag staging) ----
  const __bf16* pw = (const __bf16*)(ws + PROJ_W_OFF);
  bf16x8 pwf[2][4];
  float pb2[2];
#pragma unroll
  for (int nt2 = 0; nt2 < 2; nt2++) {
    pb2[nt2] = proj_b[wid * 32 + nt2 * 16 + lr];
#pragma unroll
    for (int kk = 0; kk < 4; kk++)
      pwf[nt2][kk] = *(const bf16x8*)(pw + ((wid * 2 + nt2) * 4 + kk) * 512 + lane * 8);
  }
  const float* btbl = (const float*)(ws + BIAS_OFF);
  f32x4 bc[4][4];
#pragma unroll
  for (int qt = 0; qt < 4; qt++)
#pragma unroll
    for (int kt = 0; kt < 4; kt++)
      bc[qt][kt] = *(const f32x4*)(btbl + ((wid * 4 + qt) * 4 + kt) * 256 + lane * 4);

  // ---- prefetch residual x for phase D (latency hides under phase C) ----
  int gidx[4][4];
#pragma unroll
  for (int st = 0; st < 4; st++)
#pragma unroll
    for (int i = 0; i < 4; i++) {
      int rr = st * 16 + lk * 4 + i;
      int io = (wi * 8 + (rr >> 3) + SS) & 511;
      int jo = (wj * 8 + (rr & 7) + SS) & 511;
      gidx[st][i] = io * 512 + jo;
    }
  float xres[4][2][4];
#pragma unroll
  for (int st = 0; st < 4; st++)
#pragma unroll
    for (int nt2 = 0; nt2 < 2; nt2++)
#pragma unroll
      for (int i = 0; i < 4; i++)
        xres[st][nt2][i] = x[(size_t)gidx[st][i] * 128 + wid * 32 + nt2 * 16 + lr];

  // ---- Phase C: head-private attention (no barriers) ----
  {
    __bf16* reg0 = &wreg[wid][0];
    bf16x8 kf[4], qf[4], vf[2][2];
#pragma unroll
    for (int kt = 0; kt < 4; kt++)
      kf[kt] = *(const bf16x8*)(reg0 + 2560 + (kt * 16 + lr) * QKS + lk * 8);
#pragma unroll
    for (int qt = 0; qt < 4; qt++)
      qf[qt] = *(const bf16x8*)(reg0 + (qt * 16 + lr) * QKS + lk * 8);
#pragma unroll
    for (int dt = 0; dt < 2; dt++)
#pragma unroll
      for (int kk = 0; kk < 2; kk++)
        vf[dt][kk] = *(const bf16x8*)(&vt[wid][(dt * 16 + lr) * PSS + kk * 32 + lk * 8]);
    // ensure frag reads retired before overwriting region with ps
    asm volatile("s_waitcnt lgkmcnt(0)" ::: "memory");
    __builtin_amdgcn_sched_barrier(0);

    int4 rk[4];
    if (edge) {
#pragma unroll
      for (int kt = 0; kt < 4; kt++) rk[kt] = *(const int4*)&rid[kt * 16 + lk * 4];
    }

#pragma unroll
    for (int qt = 0; qt < 4; qt++) {
      f32x4 s[4];
#pragma unroll
      for (int kt = 0; kt < 4; kt++) s[kt] = MFMA16(kf[kt], qf[qt], bc[qt][kt]);
      if (edge) {
        int rq = rid[qt * 16 + lr];
#pragma unroll
        for (int kt = 0; kt < 4; kt++) {
          s[kt][0] += (rk[kt].x != rq) ? -100.f : 0.f;
          s[kt][1] += (rk[kt].y != rq) ? -100.f : 0.f;
          s[kt][2] += (rk[kt].z != rq) ? -100.f : 0.f;
          s[kt][3] += (rk[kt].w != rq) ? -100.f : 0.f;
        }
      }
      float ex[4][4];
      float sum = 0.f;
#pragma unroll
      for (int kt = 0; kt < 4; kt++) {
#pragma unroll
        for (int i = 0; i < 4; i++) { ex[kt][i] = __expf(s[kt][i]); sum += ex[kt][i]; }
      }
      sum += __shfl_xor(sum, 16);
      sum += __shfl_xor(sum, 32);
      float inv = __builtin_amdgcn_rcpf(sum);
      __bf16* psrow = reg0 + (qt * 16 + lr) * PSS;
#pragma unroll
      for (int kt = 0; kt < 4; kt++) {
        bf16x2 p01 = {(__bf16)(ex[kt][0] * inv), (__bf16)(ex[kt][1] * inv)};
        bf16x2 p23 = {(__bf16)(ex[kt][2] * inv), (__bf16)(ex[kt][3] * inv)};
        *(bf16x2*)(psrow + kt * 16 + lk * 4) = p01;
        *(bf16x2*)(psrow + kt * 16 + lk * 4 + 2) = p23;
      }
#pragma unroll
      for (int dt = 0; dt < 2; dt++) {
        bf16x8 pa0 = *(const bf16x8*)(reg0 + (qt * 16 + lr) * PSS + lk * 8);
        bf16x8 pa1 = *(const bf16x8*)(reg0 + (qt * 16 + lr) * PSS + 32 + lk * 8);
        f32x4 acc = MFMA16(pa0, vf[dt][0], zero4);
        acc = MFMA16(pa1, vf[dt][1], acc);
#pragma unroll
        for (int i = 0; i < 4; i++)
          reg0[qt * 1152 + (lk * 4 + i) * QKS + dt * 16 + lr] = (__bf16)acc[i];
      }
    }
  }
  LGKM_BARRIER();   // keep xres prefetch in flight (no vmcnt drain)

  // ---- Phase D: proj col-slice (wave owns 32 cols) + residual, inverse roll ----
  {
#pragma unroll
    for (int st = 0; st < 4; st++) {
      bf16x8 ao[4];
#pragma unroll
      for (int kk = 0; kk < 4; kk++)   // head kk's O stripe st
        ao[kk] = *(const bf16x8*)(&wreg[kk][st * 1152 + lr * QKS + lk * 8]);
#pragma unroll
      for (int nt2 = 0; nt2 < 2; nt2++) {
        f32x4 acc = zero4;
#pragma unroll
        for (int kk = 0; kk < 4; kk++) acc = MFMA16(ao[kk], pwf[nt2][kk], acc);
        int j = wid * 32 + nt2 * 16 + lr;
#pragma unroll
        for (int i = 0; i < 4; i++) {
          size_t off = (size_t)gidx[st][i] * 128 + j;
          out[off] = xres[st][nt2][i] + acc[i] + pb2[nt2];
        }
      }
    }
  }
}

// sigmoid-gelu: x * sigma(1.702x); |err| vs tanh-gelu < 0.005 for |x|<~1.5
__device__ __forceinline__ float gelu_sig(float x) {
  float e = exp2f(x * -2.4554826f);   // 1.702 * log2(e)
  return x * __builtin_amdgcn_rcpf(1.f + e);
}

__global__ __launch_bounds__(512, 4) void mlp_kernel(
    const float* __restrict__ ln2_w, const float* __restrict__ ln2_b,
    const float* __restrict__ mlp_b1, const float* __restrict__ mlp_b2,
    const unsigned char* __restrict__ ws, float* __restrict__ out) {
  __shared__ __attribute__((aligned(16))) __bf16 xn[64 * 128];  // LN2 out, swizzled (16 KB)
  __shared__ __attribute__((aligned(16))) __bf16 hb[64 * 256];  // gelu(h) chunk, swizzled (32 KB)
  __shared__ __attribute__((aligned(16))) __bf16 x1b[64 * X1S]; // x1 stash bf16 (17.5 KB)
  const int tid = threadIdx.x;
  const int wid = tid >> 6, lane = tid & 63;
  const int lr = lane & 15, lk = lane >> 4;
  const f32x4 zero4 = {0.f, 0.f, 0.f, 0.f};
  const int row0 = blockIdx.x * 64;

  const __bf16* w1r = (const __bf16*)(ws + W1_OFF);
  const __bf16* w2r = (const __bf16*)(ws + W2_OFF);

  // NO persistent weight registers (spill-proof); only biases.
  float b1v[2][2];
#pragma unroll
  for (int c = 0; c < 2; c++)
#pragma unroll
    for (int nt = 0; nt < 2; nt++)
      b1v[c][nt] = mlp_b1[c * 256 + wid * 32 + nt * 16 + lr];
  float b2v = mlp_b2[wid * 16 + lr];

  // ---- LN2 (8 threads/row, 16 elems each) + x1 stash ----
  {
    int n = tid >> 3, q = tid & 7;
    const float4* xp = (const float4*)(out + (size_t)(row0 + n) * 128 + q * 16);
    float4 xv[4];
    float s = 0.f, s2 = 0.f;
#pragma unroll
    for (int t = 0; t < 4; t++) {
      float4 v = xp[t]; xv[t] = v;
      s += v.x + v.y + v.z + v.w;
      s2 += v.x * v.x + v.y * v.y + v.z * v.z + v.w * v.w;
    }
    s += __shfl_xor(s, 1); s += __shfl_xor(s, 2); s += __shfl_xor(s, 4);
    s2 += __shfl_xor(s2, 1); s2 += __shfl_xor(s2, 2); s2 += __shfl_xor(s2, 4);
    float mean = s * (1.f / 128.f);
    float var = s2 * (1.f / 128.f) - mean * mean;
    float rstd = rsqrtf(var + 1e-5f);
    const float4* wv = (const float4*)(ln2_w + q * 16);
    const float4* bv = (const float4*)(ln2_b + q * 16);
    bf16x8 o[2], r[2];
#pragma unroll
    for (int t = 0; t < 4; t++) {
      float4 wt = wv[t], bt = bv[t], v = xv[t];
      o[t >> 1][(t & 1) * 4 + 0] = (__bf16)((v.x - mean) * rstd * wt.x + bt.x);
      o[t >> 1][(t & 1) * 4 + 1] = (__bf16)((v.y - mean) * rstd * wt.y + bt.y);
      o[t >> 1][(t & 1) * 4 + 2] = (__bf16)((v.z - mean) * rstd * wt.z + bt.z);
      o[t >> 1][(t & 1) * 4 + 3] = (__bf16)((v.w - mean) * rstd * wt.w + bt.w);
      r[t >> 1][(t & 1) * 4 + 0] = (__bf16)v.x;
      r[t >> 1][(t & 1) * 4 + 1] = (__bf16)v.y;
      r[t >> 1][(t & 1) * 4 + 2] = (__bf16)v.z;
      r[t >> 1][(t & 1) * 4 + 3] = (__bf16)v.w;
    }
    *(bf16x8*)(xn + n * 128 + (((q * 2 + 0) ^ (n & 15)) << 3)) = o[0];
    *(bf16x8*)(xn + n * 128 + (((q * 2 + 1) ^ (n & 15)) << 3)) = o[1];
    *(bf16x8*)(x1b + n * X1S + q * 16) = r[0];
    *(bf16x8*)(x1b + n * X1S + q * 16 + 8) = r[1];
  }
  __syncthreads();

  f32x4 macc[4] = {zero4, zero4, zero4, zero4};

#pragma unroll 1
  for (int c = 0; c < 2; c++) {
    // stream this chunk's w1 AND w2 frags (64 VGPR transient, reused over 4 st)
    bf16x8 w1f[2][4], w2f[8];
#pragma unroll
    for (int nt = 0; nt < 2; nt++)
#pragma unroll
      for (int kk = 0; kk < 4; kk++)
        w1f[nt][kk] = *(const bf16x8*)(w1r + (((c * 8 + wid) * 2 + nt) * 4 + kk) * 512 + lane * 8);
#pragma unroll
    for (int kks = 0; kks < 8; kks++)
      w2f[kks] = *(const bf16x8*)(w2r + (wid * 16 + c * 8 + kks) * 512 + lane * 8);

    // ---- fc1 + gelu -> hb chunk (wave owns 32 hidden cols) ----
#pragma unroll
    for (int st = 0; st < 4; st++) {
      bf16x8 a1[4];
#pragma unroll
      for (int kk = 0; kk < 4; kk++)
        a1[kk] = *(const bf16x8*)(xn + (st * 16 + lr) * 128 + (((kk * 4 + lk) ^ lr) << 3));
#pragma unroll
      for (int nt = 0; nt < 2; nt++) {
        f32x4 acc = zero4;
#pragma unroll
        for (int kk = 0; kk < 4; kk++) acc = MFMA16(a1[kk], w1f[nt][kk], acc);
        int slot = wid * 4 + nt * 2 + (lr >> 3);
#pragma unroll
        for (int i = 0; i < 4; i++) {
          int row = st * 16 + lk * 4 + i;
          hb[row * 256 + ((slot ^ (row & 15)) << 3) + (lr & 7)] =
              (__bf16)gelu_sig(acc[i] + b1v[c][nt]);
        }
      }
    }
    __syncthreads();

    // ---- fc2 partial over this chunk's K=256 ----
#pragma unroll
    for (int st = 0; st < 4; st++) {
#pragma unroll
      for (int kks = 0; kks < 8; kks++) {
        bf16x8 ah = *(const bf16x8*)(hb + (st * 16 + lr) * 256 + (((kks * 4 + lk) ^ lr) << 3));
        macc[st] = MFMA16(ah, w2f[kks], macc[st]);
      }
    }
    if (c == 0) __syncthreads();  // protect hb overwrite by chunk-1 fc1
  }

  // ---- epilogue: PURE WRITE out = x1(stash) + fc2 + b2 ----
#pragma unroll
  for (int st = 0; st < 4; st++)
#pragma unroll
    for (int i = 0; i < 4; i++) {
      int row = st * 16 + lk * 4 + i;
      float x1v = (float)x1b[row * X1S + wid * 16 + lr];
      out[(size_t)(row0 + row) * 128 + wid * 16 + lr] = x1v + macc[st][i] + b2v;
    }
}

extern "C" void kernel_launch(void* const* d_in, const int* in_sizes, int n_in,
                              void* d_out, int out_size, void* d_ws, size_t ws_size,
                              hipStream_t stream) {
  const float* x      = (const float*)d_in[0];
  const float* ln1_w  = (const float*)d_in[1];
  const float* ln1_b  = (const float*)d_in[2];
  const float* qkv_w  = (const float*)d_in[3];
  const float* qkv_b  = (const float*)d_in[4];
  const float* rel_b  = (const float*)d_in[5];
  const float* proj_w = (const float*)d_in[6];
  const float* proj_b = (const float*)d_in[7];
  const float* ln2_w  = (const float*)d_in[8];
  const float* ln2_b  = (const float*)d_in[9];
  const float* mlp_w1 = (const float*)d_in[10];
  const float* mlp_b1 = (const float*)d_in[11];
  const float* mlp_w2 = (const float*)d_in[12];
  const float* mlp_b2 = (const float*)d_in[13];
  float* out = (float*)d_out;
  unsigned char* ws = (unsigned char*)d_ws;

  prep_kernel<<<256, 256, 0, stream>>>(qkv_w, proj_w, mlp_w1, mlp_w2, rel_b, ws);
  attn_kernel<<<4096, 256, 0, stream>>>(x, ln1_w, ln1_b, qkv_b, proj_b, ws, out);
  mlp_kernel<<<4096, 512, 0, stream>>>(ln2_w, ln2_b, mlp_b1, mlp_b2, ws, out);
}

// Round 10
// 283.788 us; speedup vs baseline: 1.2997x; 1.2997x over previous
//
#include <hip/hip_runtime.h>
#include <hip/hip_bf16.h>

// FBANetLayer: Swin-style block. H=W=512, DIM=128, WL=8, SS=4, HEADS=4, HD=32.
// attn: head-per-wave; swapped-QK^T scores with bias C-init; max-free softmax;
//       wave-private LDS; residual prefetch; raw lgkm-only barriers.
// mlp:  grid 4096 x 1 tile(64 rows); w1/w2 frags streamed per hidden-chunk;
//       x1 stashed bf16 in LDS; epilogue STAGED through LDS (hb reused as
//       f32) then LINE-COMPLETE 1KB/wave dwordx4 stores -- no partial-line
//       cold writes (round-9's 3.4x write amplification).

typedef __bf16 bf16x8 __attribute__((ext_vector_type(8)));
typedef __bf16 bf16x2 __attribute__((ext_vector_type(2)));
typedef float f32x4 __attribute__((ext_vector_type(4)));

#define MFMA16(a, b, c) __builtin_amdgcn_mfma_f32_16x16x32_bf16(a, b, c, 0, 0, 0)
#define LGKM_BARRIER() do { \
    asm volatile("s_waitcnt lgkmcnt(0)" ::: "memory"); \
    __builtin_amdgcn_s_barrier(); } while (0)

#define SS 4
#define XS 136   // attn LDS stride (bf16) for the 128-wide xn tile (2-way banks)
#define QKS 40   // stride for 32-wide q/k/O tiles (2-way banks)
#define PSS 72   // stride for 64-wide ps / vt tiles (2-way banks)
#define X1S 140  // mlp x1-stash stride

// ws byte offsets (total 458,752 B)
#define QKV_W_OFF 0        // 384x128 bf16 frag-order: ((h*6+nt)*4+kk)*512 + lane*8
#define PROJ_W_OFF 98304   // 128x128 bf16 frag-order: ((wid*2+nt2)*4+kk)*512 + lane*8
#define W1_OFF 131072      // 512x128 bf16 frag-order (chunked): (((c*8+wid)*2+nt)*4+kk)*512+lane*8
#define W2_OFF 262144      // 128x512 bf16 frag-order: (wid*16+kk)*512 + lane*8
#define BIAS_OFF 393216    // bias C-frag table: f32[((h*4+qt)*4+kt)*256 + lane*4 + i]

__device__ __forceinline__ int regid(int u) { return (u >= 508) ? 2 : ((u >= 504) ? 1 : 0); }

__global__ __launch_bounds__(256) void prep_kernel(
    const float* __restrict__ qkv_w, const float* __restrict__ proj_w,
    const float* __restrict__ w1, const float* __restrict__ w2,
    const float* __restrict__ rel_bias, unsigned char* __restrict__ ws) {
  int tid = blockIdx.x * 256 + threadIdx.x;
  __bf16* qw = (__bf16*)(ws + QKV_W_OFF);
  __bf16* pw = (__bf16*)(ws + PROJ_W_OFF);
  __bf16* w1b = (__bf16*)(ws + W1_OFF);
  __bf16* w2b = (__bf16*)(ws + W2_OFF);
  float* btbl = (float*)(ws + BIAS_OFF);
  if (tid < 49152) {
    int e = tid & 7, lane = (tid >> 3) & 63, kk = (tid >> 9) & 3;
    int f = tid >> 11;            // 0..23 = h*6+nt
    int h = f / 6, nt = f % 6;
    int j = (nt >> 1) * 128 + h * 32 + (nt & 1) * 16 + (lane & 15);
    int k = kk * 32 + (lane >> 4) * 8 + e;
    qw[tid] = (__bf16)qkv_w[j * 128 + k];
  }
  if (tid < 16384) {
    int e = tid & 7, lane = (tid >> 3) & 63, kk = (tid >> 9) & 3;
    int nt2 = (tid >> 11) & 1, wid = (tid >> 12) & 3;
    int j = wid * 32 + nt2 * 16 + (lane & 15);
    int k = kk * 32 + (lane >> 4) * 8 + e;
    pw[tid] = (__bf16)proj_w[j * 128 + k];
  }
  if (tid < 65536) {
    { // w1 chunked frag order: c,wid,nt,kk
      int e = tid & 7, lane = (tid >> 3) & 63, kk = (tid >> 9) & 3;
      int nt = (tid >> 11) & 1, wid = (tid >> 12) & 7, c = (tid >> 15) & 1;
      int j = c * 256 + wid * 32 + nt * 16 + (lane & 15);
      int k = kk * 32 + (lane >> 4) * 8 + e;
      w1b[tid] = (__bf16)w1[j * 128 + k]; }
    { int e = tid & 7, lane = (tid >> 3) & 63, kk = (tid >> 9) & 15, wid = (tid >> 13) & 7;
      int j = wid * 16 + (lane & 15);
      int k = kk * 32 + (lane >> 4) * 8 + e;
      w2b[tid] = (__bf16)w2[j * 512 + k]; }
  }
  if (tid < 16384) {
    // bias C-frag table: lane holds C[row=k-tok=(l>>4)*4+i][col=q-tok=l&15]
    int i = tid & 3, lane = (tid >> 2) & 63;
    int kt = (tid >> 8) & 3, qt = (tid >> 10) & 3, h = (tid >> 12) & 3;
    int n = qt * 16 + (lane & 15);          // q token
    int m = kt * 16 + (lane >> 4) * 4 + i;  // k token
    int idx = ((n >> 3) - (m >> 3) + 7) * 15 + ((n & 7) - (m & 7) + 7);
    btbl[tid] = rel_bias[idx * 4 + h];
  }
}

__global__ __launch_bounds__(256, 2) void attn_kernel(
    const float* __restrict__ x, const float* __restrict__ ln1_w, const float* __restrict__ ln1_b,
    const float* __restrict__ qkv_b, const float* __restrict__ proj_b,
    const unsigned char* __restrict__ ws, float* __restrict__ out) {
  __shared__ __attribute__((aligned(16))) __bf16 xn[64 * XS];   // 17,408 B
  __shared__ __attribute__((aligned(16))) __bf16 wreg[4][5120]; // 4 x 10,240 B
  __shared__ __attribute__((aligned(16))) __bf16 vt[4][32 * PSS]; // 4 x 4,608 B
  __shared__ __attribute__((aligned(16))) int rid[64];

  const int w = blockIdx.x;
  const int wi = w >> 6, wj = w & 63;
  const int tid = threadIdx.x;
  const int wid = tid >> 6, lane = tid & 63;
  const int lr = lane & 15, lk = lane >> 4;
  const bool edge = (wi == 63) || (wj == 63);
  const f32x4 zero4 = {0.f, 0.f, 0.f, 0.f};

  // ---- Hoisted QKV B-frags: wave wid's head slice {Q_h,K_h,V_h} ----
  const __bf16* qw = (const __bf16*)(ws + QKV_W_OFF);
  bf16x8 bw[6][4];
  float qb[6];
#pragma unroll
  for (int nt = 0; nt < 6; nt++) {
    qb[nt] = qkv_b[(nt >> 1) * 128 + wid * 32 + (nt & 1) * 16 + lr];
#pragma unroll
    for (int kk = 0; kk < 4; kk++)
      bw[nt][kk] = *(const bf16x8*)(qw + ((wid * 6 + nt) * 4 + kk) * 512 + lane * 8);
  }

  // ---- Phase A: gather rolled rows + LN1 -> bf16 LDS ----
  {
    int n = tid >> 2, q = tid & 3;
    int r = n >> 3, c = n & 7;
    int io = (wi * 8 + r + SS) & 511;
    int jo = (wj * 8 + c + SS) & 511;
    size_t gid = (size_t)io * 512 + jo;
    const float4* xp = (const float4*)(x + gid * 128 + q * 32);
    float4 xv[8];
    float s = 0.f, s2 = 0.f;
#pragma unroll
    for (int t = 0; t < 8; t++) {
      float4 v = xp[t]; xv[t] = v;
      s += v.x + v.y + v.z + v.w;
      s2 += v.x * v.x + v.y * v.y + v.z * v.z + v.w * v.w;
    }
    s += __shfl_xor(s, 1); s += __shfl_xor(s, 2);
    s2 += __shfl_xor(s2, 1); s2 += __shfl_xor(s2, 2);
    float mean = s * (1.f / 128.f);
    float var = s2 * (1.f / 128.f) - mean * mean;
    float rstd = rsqrtf(var + 1e-5f);
    const float4* wv = (const float4*)(ln1_w + q * 32);
    const float4* bv = (const float4*)(ln1_b + q * 32);
    __bf16* dst = xn + n * XS + q * 32;
#pragma unroll
    for (int t = 0; t < 8; t++) {
      float4 wt = wv[t], bt = bv[t], v = xv[t];
      dst[t * 4 + 0] = (__bf16)((v.x - mean) * rstd * wt.x + bt.x);
      dst[t * 4 + 1] = (__bf16)((v.y - mean) * rstd * wt.y + bt.y);
      dst[t * 4 + 2] = (__bf16)((v.z - mean) * rstd * wt.z + bt.z);
      dst[t * 4 + 3] = (__bf16)((v.w - mean) * rstd * wt.w + bt.w);
    }
    if (q == 0) rid[n] = 3 * regid(wi * 8 + r) + regid(wj * 8 + c);
  }
  LGKM_BARRIER();   // keep hoisted bw loads in flight (no vmcnt drain)

  // ---- Phase B: QKV for head wid (64 rows x 96 cols), into private LDS ----
  {
    const float scale = 0.17677669529663687f;  // 32^-0.5 folded into Q
    __bf16* qbase = &wreg[wid][0];
    __bf16* kbase = &wreg[wid][2560];
    __bf16* vbase = &vt[wid][0];
#pragma unroll
    for (int st = 0; st < 4; st++) {
      bf16x8 a[4];
#pragma unroll
      for (int kk = 0; kk < 4; kk++)
        a[kk] = *(const bf16x8*)(xn + (st * 16 + lr) * XS + kk * 32 + lk * 8);
#pragma unroll
      for (int nt = 0; nt < 6; nt++) {
        f32x4 acc = zero4;
#pragma unroll
        for (int kk = 0; kk < 4; kk++) acc = MFMA16(a[kk], bw[nt][kk], acc);
        float bias = qb[nt];
        int dl = (nt & 1) * 16 + lr;           // d_local within head
        if (nt < 2) {
#pragma unroll
          for (int i = 0; i < 4; i++)
            qbase[(st * 16 + lk * 4 + i) * QKS + dl] = (__bf16)((acc[i] + bias) * scale);
        } else if (nt < 4) {
#pragma unroll
          for (int i = 0; i < 4; i++)
            kbase[(st * 16 + lk * 4 + i) * QKS + dl] = (__bf16)(acc[i] + bias);
        } else {
#pragma unroll
          for (int i = 0; i < 4; i++)
            vbase[dl * PSS + st * 16 + lk * 4 + i] = (__bf16)(acc[i] + bias);
        }
      }
    }
  }

  // ---- hoist proj B-frags + bias C-frags (loads overlap frag staging) ----
  const __bf16* pw = (const __bf16*)(ws + PROJ_W_OFF);
  bf16x8 pwf[2][4];
  float pb2[2];
#pragma unroll
  for (int nt2 = 0; nt2 < 2; nt2++) {
    pb2[nt2] = proj_b[wid * 32 + nt2 * 16 + lr];
#pragma unroll
    for (int kk = 0; kk < 4; kk++)
      pwf[nt2][kk] = *(const bf16x8*)(pw + ((wid * 2 + nt2) * 4 + kk) * 512 + lane * 8);
  }
  const float* btbl = (const float*)(ws + BIAS_OFF);
  f32x4 bc[4][4];
#pragma unroll
  for (int qt = 0; qt < 4; qt++)
#pragma unroll
    for (int kt = 0; kt < 4; kt++)
      bc[qt][kt] = *(const f32x4*)(btbl + ((wid * 4 + qt) * 4 + kt) * 256 + lane * 4);

  // ---- prefetch residual x for phase D (latency hides under phase C) ----
  int gidx[4][4];
#pragma unroll
  for (int st = 0; st < 4; st++)
#pragma unroll
    for (int i = 0; i < 4; i++) {
      int rr = st * 16 + lk * 4 + i;
      int io = (wi * 8 + (rr >> 3) + SS) & 511;
      int jo = (wj * 8 + (rr & 7) + SS) & 511;
      gidx[st][i] = io * 512 + jo;
    }
  float xres[4][2][4];
#pragma unroll
  for (int st = 0; st < 4; st++)
#pragma unroll
    for (int nt2 = 0; nt2 < 2; nt2++)
#pragma unroll
      for (int i = 0; i < 4; i++)
        xres[st][nt2][i] = x[(size_t)gidx[st][i] * 128 + wid * 32 + nt2 * 16 + lr];

  // ---- Phase C: head-private attention (no barriers) ----
  {
    __bf16* reg0 = &wreg[wid][0];
    bf16x8 kf[4], qf[4], vf[2][2];
#pragma unroll
    for (int kt = 0; kt < 4; kt++)
      kf[kt] = *(const bf16x8*)(reg0 + 2560 + (kt * 16 + lr) * QKS + lk * 8);
#pragma unroll
    for (int qt = 0; qt < 4; qt++)
      qf[qt] = *(const bf16x8*)(reg0 + (qt * 16 + lr) * QKS + lk * 8);
#pragma unroll
    for (int dt = 0; dt < 2; dt++)
#pragma unroll
      for (int kk = 0; kk < 2; kk++)
        vf[dt][kk] = *(const bf16x8*)(&vt[wid][(dt * 16 + lr) * PSS + kk * 32 + lk * 8]);
    // ensure frag reads retired before overwriting region with ps
    asm volatile("s_waitcnt lgkmcnt(0)" ::: "memory");
    __builtin_amdgcn_sched_barrier(0);

    int4 rk[4];
    if (edge) {
#pragma unroll
      for (int kt = 0; kt < 4; kt++) rk[kt] = *(const int4*)&rid[kt * 16 + lk * 4];
    }

#pragma unroll
    for (int qt = 0; qt < 4; qt++) {
      f32x4 s[4];
#pragma unroll
      for (int kt = 0; kt < 4; kt++) s[kt] = MFMA16(kf[kt], qf[qt], bc[qt][kt]);
      if (edge) {
        int rq = rid[qt * 16 + lr];
#pragma unroll
        for (int kt = 0; kt < 4; kt++) {
          s[kt][0] += (rk[kt].x != rq) ? -100.f : 0.f;
          s[kt][1] += (rk[kt].y != rq) ? -100.f : 0.f;
          s[kt][2] += (rk[kt].z != rq) ? -100.f : 0.f;
          s[kt][3] += (rk[kt].w != rq) ? -100.f : 0.f;
        }
      }
      float ex[4][4];
      float sum = 0.f;
#pragma unroll
      for (int kt = 0; kt < 4; kt++) {
#pragma unroll
        for (int i = 0; i < 4; i++) { ex[kt][i] = __expf(s[kt][i]); sum += ex[kt][i]; }
      }
      sum += __shfl_xor(sum, 16);
      sum += __shfl_xor(sum, 32);
      float inv = __builtin_amdgcn_rcpf(sum);
      __bf16* psrow = reg0 + (qt * 16 + lr) * PSS;
#pragma unroll
      for (int kt = 0; kt < 4; kt++) {
        bf16x2 p01 = {(__bf16)(ex[kt][0] * inv), (__bf16)(ex[kt][1] * inv)};
        bf16x2 p23 = {(__bf16)(ex[kt][2] * inv), (__bf16)(ex[kt][3] * inv)};
        *(bf16x2*)(psrow + kt * 16 + lk * 4) = p01;
        *(bf16x2*)(psrow + kt * 16 + lk * 4 + 2) = p23;
      }
#pragma unroll
      for (int dt = 0; dt < 2; dt++) {
        bf16x8 pa0 = *(const bf16x8*)(reg0 + (qt * 16 + lr) * PSS + lk * 8);
        bf16x8 pa1 = *(const bf16x8*)(reg0 + (qt * 16 + lr) * PSS + 32 + lk * 8);
        f32x4 acc = MFMA16(pa0, vf[dt][0], zero4);
        acc = MFMA16(pa1, vf[dt][1], acc);
#pragma unroll
        for (int i = 0; i < 4; i++)
          reg0[qt * 1152 + (lk * 4 + i) * QKS + dt * 16 + lr] = (__bf16)acc[i];
      }
    }
  }
  LGKM_BARRIER();   // keep xres prefetch in flight (no vmcnt drain)

  // ---- Phase D: proj col-slice (wave owns 32 cols) + residual, inverse roll ----
  {
#pragma unroll
    for (int st = 0; st < 4; st++) {
      bf16x8 ao[4];
#pragma unroll
      for (int kk = 0; kk < 4; kk++)   // head kk's O stripe st
        ao[kk] = *(const bf16x8*)(&wreg[kk][st * 1152 + lr * QKS + lk * 8]);
#pragma unroll
      for (int nt2 = 0; nt2 < 2; nt2++) {
        f32x4 acc = zero4;
#pragma unroll
        for (int kk = 0; kk < 4; kk++) acc = MFMA16(ao[kk], pwf[nt2][kk], acc);
        int j = wid * 32 + nt2 * 16 + lr;
#pragma unroll
        for (int i = 0; i < 4; i++) {
          size_t off = (size_t)gidx[st][i] * 128 + j;
          out[off] = xres[st][nt2][i] + acc[i] + pb2[nt2];
        }
      }
    }
  }
}

// sigmoid-gelu: x * sigma(1.702x); |err| vs tanh-gelu < 0.005 for |x|<~1.5
__device__ __forceinline__ float gelu_sig(float x) {
  float e = exp2f(x * -2.4554826f);   // 1.702 * log2(e)
  return x * __builtin_amdgcn_rcpf(1.f + e);
}

__global__ __launch_bounds__(512, 4) void mlp_kernel(
    const float* __restrict__ ln2_w, const float* __restrict__ ln2_b,
    const float* __restrict__ mlp_b1, const float* __restrict__ mlp_b2,
    const unsigned char* __restrict__ ws, float* __restrict__ out) {
  __shared__ __attribute__((aligned(16))) __bf16 xn[64 * 128];  // LN2 out, swizzled (16 KB)
  __shared__ __attribute__((aligned(16))) __bf16 hb[64 * 256];  // gelu chunk; reused as f32 stage
  __shared__ __attribute__((aligned(16))) __bf16 x1b[64 * X1S]; // x1 stash bf16 (17.5 KB)
  const int tid = threadIdx.x;
  const int wid = tid >> 6, lane = tid & 63;
  const int lr = lane & 15, lk = lane >> 4;
  const f32x4 zero4 = {0.f, 0.f, 0.f, 0.f};
  const int row0 = blockIdx.x * 64;

  const __bf16* w1r = (const __bf16*)(ws + W1_OFF);
  const __bf16* w2r = (const __bf16*)(ws + W2_OFF);

  // NO persistent weight registers (spill-proof); only biases.
  float b1v[2][2];
#pragma unroll
  for (int c = 0; c < 2; c++)
#pragma unroll
    for (int nt = 0; nt < 2; nt++)
      b1v[c][nt] = mlp_b1[c * 256 + wid * 32 + nt * 16 + lr];
  float b2v = mlp_b2[wid * 16 + lr];

  // ---- LN2 (8 threads/row, 16 elems each) + x1 stash ----
  {
    int n = tid >> 3, q = tid & 7;
    const float4* xp = (const float4*)(out + (size_t)(row0 + n) * 128 + q * 16);
    float4 xv[4];
    float s = 0.f, s2 = 0.f;
#pragma unroll
    for (int t = 0; t < 4; t++) {
      float4 v = xp[t]; xv[t] = v;
      s += v.x + v.y + v.z + v.w;
      s2 += v.x * v.x + v.y * v.y + v.z * v.z + v.w * v.w;
    }
    s += __shfl_xor(s, 1); s += __shfl_xor(s, 2); s += __shfl_xor(s, 4);
    s2 += __shfl_xor(s2, 1); s2 += __shfl_xor(s2, 2); s2 += __shfl_xor(s2, 4);
    float mean = s * (1.f / 128.f);
    float var = s2 * (1.f / 128.f) - mean * mean;
    float rstd = rsqrtf(var + 1e-5f);
    const float4* wv = (const float4*)(ln2_w + q * 16);
    const float4* bv = (const float4*)(ln2_b + q * 16);
    bf16x8 o[2], r[2];
#pragma unroll
    for (int t = 0; t < 4; t++) {
      float4 wt = wv[t], bt = bv[t], v = xv[t];
      o[t >> 1][(t & 1) * 4 + 0] = (__bf16)((v.x - mean) * rstd * wt.x + bt.x);
      o[t >> 1][(t & 1) * 4 + 1] = (__bf16)((v.y - mean) * rstd * wt.y + bt.y);
      o[t >> 1][(t & 1) * 4 + 2] = (__bf16)((v.z - mean) * rstd * wt.z + bt.z);
      o[t >> 1][(t & 1) * 4 + 3] = (__bf16)((v.w - mean) * rstd * wt.w + bt.w);
      r[t >> 1][(t & 1) * 4 + 0] = (__bf16)v.x;
      r[t >> 1][(t & 1) * 4 + 1] = (__bf16)v.y;
      r[t >> 1][(t & 1) * 4 + 2] = (__bf16)v.z;
      r[t >> 1][(t & 1) * 4 + 3] = (__bf16)v.w;
    }
    *(bf16x8*)(xn + n * 128 + (((q * 2 + 0) ^ (n & 15)) << 3)) = o[0];
    *(bf16x8*)(xn + n * 128 + (((q * 2 + 1) ^ (n & 15)) << 3)) = o[1];
    *(bf16x8*)(x1b + n * X1S + q * 16) = r[0];
    *(bf16x8*)(x1b + n * X1S + q * 16 + 8) = r[1];
  }
  __syncthreads();

  f32x4 macc[4] = {zero4, zero4, zero4, zero4};

#pragma unroll 1
  for (int c = 0; c < 2; c++) {
    // stream this chunk's w1 AND w2 frags (64 VGPR transient, reused over 4 st)
    bf16x8 w1f[2][4], w2f[8];
#pragma unroll
    for (int nt = 0; nt < 2; nt++)
#pragma unroll
      for (int kk = 0; kk < 4; kk++)
        w1f[nt][kk] = *(const bf16x8*)(w1r + (((c * 8 + wid) * 2 + nt) * 4 + kk) * 512 + lane * 8);
#pragma unroll
    for (int kks = 0; kks < 8; kks++)
      w2f[kks] = *(const bf16x8*)(w2r + (wid * 16 + c * 8 + kks) * 512 + lane * 8);

    // ---- fc1 + gelu -> hb chunk (wave owns 32 hidden cols) ----
#pragma unroll
    for (int st = 0; st < 4; st++) {
      bf16x8 a1[4];
#pragma unroll
      for (int kk = 0; kk < 4; kk++)
        a1[kk] = *(const bf16x8*)(xn + (st * 16 + lr) * 128 + (((kk * 4 + lk) ^ lr) << 3));
#pragma unroll
      for (int nt = 0; nt < 2; nt++) {
        f32x4 acc = zero4;
#pragma unroll
        for (int kk = 0; kk < 4; kk++) acc = MFMA16(a1[kk], w1f[nt][kk], acc);
        int slot = wid * 4 + nt * 2 + (lr >> 3);
#pragma unroll
        for (int i = 0; i < 4; i++) {
          int row = st * 16 + lk * 4 + i;
          hb[row * 256 + ((slot ^ (row & 15)) << 3) + (lr & 7)] =
              (__bf16)gelu_sig(acc[i] + b1v[c][nt]);
        }
      }
    }
    __syncthreads();

    // ---- fc2 partial over this chunk's K=256 ----
#pragma unroll
    for (int st = 0; st < 4; st++) {
#pragma unroll
      for (int kks = 0; kks < 8; kks++) {
        bf16x8 ah = *(const bf16x8*)(hb + (st * 16 + lr) * 256 + (((kks * 4 + lk) ^ lr) << 3));
        macc[st] = MFMA16(ah, w2f[kks], macc[st]);
      }
    }
    __syncthreads();  // c0: protect hb overwrite by c1 fc1; c1: protect f32 staging
  }

  // ---- epilogue: stage x1+fc2+b2 (f32) in hb, then line-complete stores ----
  {
    float* stg = (float*)hb;  // 64 x 128 f32 = 32 KB exactly
#pragma unroll
    for (int st = 0; st < 4; st++)
#pragma unroll
      for (int i = 0; i < 4; i++) {
        int row = st * 16 + lk * 4 + i;
        int col = wid * 16 + lr;
        int sp = (col >> 2) ^ (((row >> 2) & 7) << 2);  // bijective slot swizzle per row
        float x1v = (float)x1b[row * X1S + col];
        stg[row * 128 + sp * 4 + (col & 3)] = x1v + macc[st][i] + b2v;
      }
    __syncthreads();
    // each wave stores rows wid*8..wid*8+7: 1 KB contiguous per iteration,
    // every 128B line written completely by one instruction (no partial-line miss)
    int half = lane >> 5, sl = lane & 31;
#pragma unroll
    for (int it = 0; it < 4; it++) {
      int row = wid * 8 + it * 2 + half;
      int sp = sl ^ (((row >> 2) & 7) << 2);
      f32x4 v = *(const f32x4*)(stg + row * 128 + sp * 4);
      *(f32x4*)(out + (size_t)(row0 + row) * 128 + sl * 4) = v;
    }
  }
}

extern "C" void kernel_launch(void* const* d_in, const int* in_sizes, int n_in,
                              void* d_out, int out_size, void* d_ws, size_t ws_size,
                              hipStream_t stream) {
  const float* x      = (const float*)d_in[0];
  const float* ln1_w  = (const float*)d_in[1];
  const float* ln1_b  = (const float*)d_in[2];
  const float* qkv_w  = (const float*)d_in[3];
  const float* qkv_b  = (const float*)d_in[4];
  const float* rel_b  = (const float*)d_in[5];
  const float* proj_w = (const float*)d_in[6];
  const float* proj_b = (const float*)d_in[7];
  const float* ln2_w  = (const float*)d_in[8];
  const float* ln2_b  = (const float*)d_in[9];
  const float* mlp_w1 = (const float*)d_in[10];
  const float* mlp_b1 = (const float*)d_in[11];
  const float* mlp_w2 = (const float*)d_in[12];
  const float* mlp_b2 = (const float*)d_in[13];
  float* out = (float*)d_out;
  unsigned char* ws = (unsigned char*)d_ws;

  prep_kernel<<<256, 256, 0, stream>>>(qkv_w, proj_w, mlp_w1, mlp_w2, rel_b, ws);
  attn_kernel<<<4096, 256, 0, stream>>>(x, ln1_w, ln1_b, qkv_b, proj_b, ws, out);
  mlp_kernel<<<4096, 512, 0, stream>>>(ln2_w, ln2_b, mlp_b1, mlp_b2, ws, out);
}

// Round 11
// 256.348 us; speedup vs baseline: 1.4388x; 1.1070x over previous
//
#include <hip/hip_runtime.h>
#include <hip/hip_bf16.h>

// FBANetLayer: Swin-style block. H=W=512, DIM=128, WL=8, SS=4, HEADS=4, HD=32.
// attn: head-per-wave; swapped-QK^T scores with bias C-init; max-free softmax;
//       wave-private LDS; residual prefetch; raw lgkm-only barriers.
// mlp:  grid 4096 x 1 tile(64 rows); w1/w2 frags streamed DISJOINTLY (w1f live
//       only in fc1, w2f only in fc2 -- peak regs ~85 < 128 cap, kills the
//       scratch-spill write amplification seen in r7/r8/r10); x1 stash bf16;
//       epilogue staged in LDS then line-complete 1KB/wave stores.

typedef __bf16 bf16x8 __attribute__((ext_vector_type(8)));
typedef __bf16 bf16x2 __attribute__((ext_vector_type(2)));
typedef float f32x4 __attribute__((ext_vector_type(4)));

#define MFMA16(a, b, c) __builtin_amdgcn_mfma_f32_16x16x32_bf16(a, b, c, 0, 0, 0)
#define LGKM_BARRIER() do { \
    asm volatile("s_waitcnt lgkmcnt(0)" ::: "memory"); \
    __builtin_amdgcn_s_barrier(); } while (0)

#define SS 4
#define XS 136   // attn LDS stride (bf16) for the 128-wide xn tile (2-way banks)
#define QKS 40   // stride for 32-wide q/k/O tiles (2-way banks)
#define PSS 72   // stride for 64-wide ps / vt tiles (2-way banks)
#define X1S 140  // mlp x1-stash stride

// ws byte offsets (total 458,752 B)
#define QKV_W_OFF 0        // 384x128 bf16 frag-order: ((h*6+nt)*4+kk)*512 + lane*8
#define PROJ_W_OFF 98304   // 128x128 bf16 frag-order: ((wid*2+nt2)*4+kk)*512 + lane*8
#define W1_OFF 131072      // 512x128 bf16 frag-order (chunked): (((c*8+wid)*2+nt)*4+kk)*512+lane*8
#define W2_OFF 262144      // 128x512 bf16 frag-order: (wid*16+kk)*512 + lane*8
#define BIAS_OFF 393216    // bias C-frag table: f32[((h*4+qt)*4+kt)*256 + lane*4 + i]

__device__ __forceinline__ int regid(int u) { return (u >= 508) ? 2 : ((u >= 504) ? 1 : 0); }

__global__ __launch_bounds__(256) void prep_kernel(
    const float* __restrict__ qkv_w, const float* __restrict__ proj_w,
    const float* __restrict__ w1, const float* __restrict__ w2,
    const float* __restrict__ rel_bias, unsigned char* __restrict__ ws) {
  int tid = blockIdx.x * 256 + threadIdx.x;
  __bf16* qw = (__bf16*)(ws + QKV_W_OFF);
  __bf16* pw = (__bf16*)(ws + PROJ_W_OFF);
  __bf16* w1b = (__bf16*)(ws + W1_OFF);
  __bf16* w2b = (__bf16*)(ws + W2_OFF);
  float* btbl = (float*)(ws + BIAS_OFF);
  if (tid < 49152) {
    int e = tid & 7, lane = (tid >> 3) & 63, kk = (tid >> 9) & 3;
    int f = tid >> 11;            // 0..23 = h*6+nt
    int h = f / 6, nt = f % 6;
    int j = (nt >> 1) * 128 + h * 32 + (nt & 1) * 16 + (lane & 15);
    int k = kk * 32 + (lane >> 4) * 8 + e;
    qw[tid] = (__bf16)qkv_w[j * 128 + k];
  }
  if (tid < 16384) {
    int e = tid & 7, lane = (tid >> 3) & 63, kk = (tid >> 9) & 3;
    int nt2 = (tid >> 11) & 1, wid = (tid >> 12) & 3;
    int j = wid * 32 + nt2 * 16 + (lane & 15);
    int k = kk * 32 + (lane >> 4) * 8 + e;
    pw[tid] = (__bf16)proj_w[j * 128 + k];
  }
  if (tid < 65536) {
    { // w1 chunked frag order: c,wid,nt,kk
      int e = tid & 7, lane = (tid >> 3) & 63, kk = (tid >> 9) & 3;
      int nt = (tid >> 11) & 1, wid = (tid >> 12) & 7, c = (tid >> 15) & 1;
      int j = c * 256 + wid * 32 + nt * 16 + (lane & 15);
      int k = kk * 32 + (lane >> 4) * 8 + e;
      w1b[tid] = (__bf16)w1[j * 128 + k]; }
    { int e = tid & 7, lane = (tid >> 3) & 63, kk = (tid >> 9) & 15, wid = (tid >> 13) & 7;
      int j = wid * 16 + (lane & 15);
      int k = kk * 32 + (lane >> 4) * 8 + e;
      w2b[tid] = (__bf16)w2[j * 512 + k]; }
  }
  if (tid < 16384) {
    // bias C-frag table: lane holds C[row=k-tok=(l>>4)*4+i][col=q-tok=l&15]
    int i = tid & 3, lane = (tid >> 2) & 63;
    int kt = (tid >> 8) & 3, qt = (tid >> 10) & 3, h = (tid >> 12) & 3;
    int n = qt * 16 + (lane & 15);          // q token
    int m = kt * 16 + (lane >> 4) * 4 + i;  // k token
    int idx = ((n >> 3) - (m >> 3) + 7) * 15 + ((n & 7) - (m & 7) + 7);
    btbl[tid] = rel_bias[idx * 4 + h];
  }
}

__global__ __launch_bounds__(256, 2) void attn_kernel(
    const float* __restrict__ x, const float* __restrict__ ln1_w, const float* __restrict__ ln1_b,
    const float* __restrict__ qkv_b, const float* __restrict__ proj_b,
    const unsigned char* __restrict__ ws, float* __restrict__ out) {
  __shared__ __attribute__((aligned(16))) __bf16 xn[64 * XS];   // 17,408 B
  __shared__ __attribute__((aligned(16))) __bf16 wreg[4][5120]; // 4 x 10,240 B
  __shared__ __attribute__((aligned(16))) __bf16 vt[4][32 * PSS]; // 4 x 4,608 B
  __shared__ __attribute__((aligned(16))) int rid[64];

  const int w = blockIdx.x;
  const int wi = w >> 6, wj = w & 63;
  const int tid = threadIdx.x;
  const int wid = tid >> 6, lane = tid & 63;
  const int lr = lane & 15, lk = lane >> 4;
  const bool edge = (wi == 63) || (wj == 63);
  const f32x4 zero4 = {0.f, 0.f, 0.f, 0.f};

  // ---- Hoisted QKV B-frags: wave wid's head slice {Q_h,K_h,V_h} ----
  const __bf16* qw = (const __bf16*)(ws + QKV_W_OFF);
  bf16x8 bw[6][4];
  float qb[6];
#pragma unroll
  for (int nt = 0; nt < 6; nt++) {
    qb[nt] = qkv_b[(nt >> 1) * 128 + wid * 32 + (nt & 1) * 16 + lr];
#pragma unroll
    for (int kk = 0; kk < 4; kk++)
      bw[nt][kk] = *(const bf16x8*)(qw + ((wid * 6 + nt) * 4 + kk) * 512 + lane * 8);
  }

  // ---- Phase A: gather rolled rows + LN1 -> bf16 LDS ----
  {
    int n = tid >> 2, q = tid & 3;
    int r = n >> 3, c = n & 7;
    int io = (wi * 8 + r + SS) & 511;
    int jo = (wj * 8 + c + SS) & 511;
    size_t gid = (size_t)io * 512 + jo;
    const float4* xp = (const float4*)(x + gid * 128 + q * 32);
    float4 xv[8];
    float s = 0.f, s2 = 0.f;
#pragma unroll
    for (int t = 0; t < 8; t++) {
      float4 v = xp[t]; xv[t] = v;
      s += v.x + v.y + v.z + v.w;
      s2 += v.x * v.x + v.y * v.y + v.z * v.z + v.w * v.w;
    }
    s += __shfl_xor(s, 1); s += __shfl_xor(s, 2);
    s2 += __shfl_xor(s2, 1); s2 += __shfl_xor(s2, 2);
    float mean = s * (1.f / 128.f);
    float var = s2 * (1.f / 128.f) - mean * mean;
    float rstd = rsqrtf(var + 1e-5f);
    const float4* wv = (const float4*)(ln1_w + q * 32);
    const float4* bv = (const float4*)(ln1_b + q * 32);
    __bf16* dst = xn + n * XS + q * 32;
#pragma unroll
    for (int t = 0; t < 8; t++) {
      float4 wt = wv[t], bt = bv[t], v = xv[t];
      dst[t * 4 + 0] = (__bf16)((v.x - mean) * rstd * wt.x + bt.x);
      dst[t * 4 + 1] = (__bf16)((v.y - mean) * rstd * wt.y + bt.y);
      dst[t * 4 + 2] = (__bf16)((v.z - mean) * rstd * wt.z + bt.z);
      dst[t * 4 + 3] = (__bf16)((v.w - mean) * rstd * wt.w + bt.w);
    }
    if (q == 0) rid[n] = 3 * regid(wi * 8 + r) + regid(wj * 8 + c);
  }
  LGKM_BARRIER();   // keep hoisted bw loads in flight (no vmcnt drain)

  // ---- Phase B: QKV for head wid (64 rows x 96 cols), into private LDS ----
  {
    const float scale = 0.17677669529663687f;  // 32^-0.5 folded into Q
    __bf16* qbase = &wreg[wid][0];
    __bf16* kbase = &wreg[wid][2560];
    __bf16* vbase = &vt[wid][0];
#pragma unroll
    for (int st = 0; st < 4; st++) {
      bf16x8 a[4];
#pragma unroll
      for (int kk = 0; kk < 4; kk++)
        a[kk] = *(const bf16x8*)(xn + (st * 16 + lr) * XS + kk * 32 + lk * 8);
#pragma unroll
      for (int nt = 0; nt < 6; nt++) {
        f32x4 acc = zero4;
#pragma unroll
        for (int kk = 0; kk < 4; kk++) acc = MFMA16(a[kk], bw[nt][kk], acc);
        float bias = qb[nt];
        int dl = (nt & 1) * 16 + lr;           // d_local within head
        if (nt < 2) {
#pragma unroll
          for (int i = 0; i < 4; i++)
            qbase[(st * 16 + lk * 4 + i) * QKS + dl] = (__bf16)((acc[i] + bias) * scale);
        } else if (nt < 4) {
#pragma unroll
          for (int i = 0; i < 4; i++)
            kbase[(st * 16 + lk * 4 + i) * QKS + dl] = (__bf16)(acc[i] + bias);
        } else {
#pragma unroll
          for (int i = 0; i < 4; i++)
            vbase[dl * PSS + st * 16 + lk * 4 + i] = (__bf16)(acc[i] + bias);
        }
      }
    }
  }

  // ---- hoist proj B-frags + bias C-frags (loads overlap frag staging) ----
  const __bf16* pw = (const __bf16*)(ws + PROJ_W_OFF);
  bf16x8 pwf[2][4];
  float pb2[2];
#pragma unroll
  for (int nt2 = 0; nt2 < 2; nt2++) {
    pb2[nt2] = proj_b[wid * 32 + nt2 * 16 + lr];
#pragma unroll
    for (int kk = 0; kk < 4; kk++)
      pwf[nt2][kk] = *(const bf16x8*)(pw + ((wid * 2 + nt2) * 4 + kk) * 512 + lane * 8);
  }
  const float* btbl = (const float*)(ws + BIAS_OFF);
  f32x4 bc[4][4];
#pragma unroll
  for (int qt = 0; qt < 4; qt++)
#pragma unroll
    for (int kt = 0; kt < 4; kt++)
      bc[qt][kt] = *(const f32x4*)(btbl + ((wid * 4 + qt) * 4 + kt) * 256 + lane * 4);

  // ---- prefetch residual x for phase D (latency hides under phase C) ----
  int gidx[4][4];
#pragma unroll
  for (int st = 0; st < 4; st++)
#pragma unroll
    for (int i = 0; i < 4; i++) {
      int rr = st * 16 + lk * 4 + i;
      int io = (wi * 8 + (rr >> 3) + SS) & 511;
      int jo = (wj * 8 + (rr & 7) + SS) & 511;
      gidx[st][i] = io * 512 + jo;
    }
  float xres[4][2][4];
#pragma unroll
  for (int st = 0; st < 4; st++)
#pragma unroll
    for (int nt2 = 0; nt2 < 2; nt2++)
#pragma unroll
      for (int i = 0; i < 4; i++)
        xres[st][nt2][i] = x[(size_t)gidx[st][i] * 128 + wid * 32 + nt2 * 16 + lr];

  // ---- Phase C: head-private attention (no barriers) ----
  {
    __bf16* reg0 = &wreg[wid][0];
    bf16x8 kf[4], qf[4], vf[2][2];
#pragma unroll
    for (int kt = 0; kt < 4; kt++)
      kf[kt] = *(const bf16x8*)(reg0 + 2560 + (kt * 16 + lr) * QKS + lk * 8);
#pragma unroll
    for (int qt = 0; qt < 4; qt++)
      qf[qt] = *(const bf16x8*)(reg0 + (qt * 16 + lr) * QKS + lk * 8);
#pragma unroll
    for (int dt = 0; dt < 2; dt++)
#pragma unroll
      for (int kk = 0; kk < 2; kk++)
        vf[dt][kk] = *(const bf16x8*)(&vt[wid][(dt * 16 + lr) * PSS + kk * 32 + lk * 8]);
    // ensure frag reads retired before overwriting region with ps
    asm volatile("s_waitcnt lgkmcnt(0)" ::: "memory");
    __builtin_amdgcn_sched_barrier(0);

    int4 rk[4];
    if (edge) {
#pragma unroll
      for (int kt = 0; kt < 4; kt++) rk[kt] = *(const int4*)&rid[kt * 16 + lk * 4];
    }

#pragma unroll
    for (int qt = 0; qt < 4; qt++) {
      f32x4 s[4];
#pragma unroll
      for (int kt = 0; kt < 4; kt++) s[kt] = MFMA16(kf[kt], qf[qt], bc[qt][kt]);
      if (edge) {
        int rq = rid[qt * 16 + lr];
#pragma unroll
        for (int kt = 0; kt < 4; kt++) {
          s[kt][0] += (rk[kt].x != rq) ? -100.f : 0.f;
          s[kt][1] += (rk[kt].y != rq) ? -100.f : 0.f;
          s[kt][2] += (rk[kt].z != rq) ? -100.f : 0.f;
          s[kt][3] += (rk[kt].w != rq) ? -100.f : 0.f;
        }
      }
      float ex[4][4];
      float sum = 0.f;
#pragma unroll
      for (int kt = 0; kt < 4; kt++) {
#pragma unroll
        for (int i = 0; i < 4; i++) { ex[kt][i] = __expf(s[kt][i]); sum += ex[kt][i]; }
      }
      sum += __shfl_xor(sum, 16);
      sum += __shfl_xor(sum, 32);
      float inv = __builtin_amdgcn_rcpf(sum);
      __bf16* psrow = reg0 + (qt * 16 + lr) * PSS;
#pragma unroll
      for (int kt = 0; kt < 4; kt++) {
        bf16x2 p01 = {(__bf16)(ex[kt][0] * inv), (__bf16)(ex[kt][1] * inv)};
        bf16x2 p23 = {(__bf16)(ex[kt][2] * inv), (__bf16)(ex[kt][3] * inv)};
        *(bf16x2*)(psrow + kt * 16 + lk * 4) = p01;
        *(bf16x2*)(psrow + kt * 16 + lk * 4 + 2) = p23;
      }
#pragma unroll
      for (int dt = 0; dt < 2; dt++) {
        bf16x8 pa0 = *(const bf16x8*)(reg0 + (qt * 16 + lr) * PSS + lk * 8);
        bf16x8 pa1 = *(const bf16x8*)(reg0 + (qt * 16 + lr) * PSS + 32 + lk * 8);
        f32x4 acc = MFMA16(pa0, vf[dt][0], zero4);
        acc = MFMA16(pa1, vf[dt][1], acc);
#pragma unroll
        for (int i = 0; i < 4; i++)
          reg0[qt * 1152 + (lk * 4 + i) * QKS + dt * 16 + lr] = (__bf16)acc[i];
      }
    }
  }
  LGKM_BARRIER();   // keep xres prefetch in flight (no vmcnt drain)

  // ---- Phase D: proj col-slice (wave owns 32 cols) + residual, inverse roll ----
  {
#pragma unroll
    for (int st = 0; st < 4; st++) {
      bf16x8 ao[4];
#pragma unroll
      for (int kk = 0; kk < 4; kk++)   // head kk's O stripe st
        ao[kk] = *(const bf16x8*)(&wreg[kk][st * 1152 + lr * QKS + lk * 8]);
#pragma unroll
      for (int nt2 = 0; nt2 < 2; nt2++) {
        f32x4 acc = zero4;
#pragma unroll
        for (int kk = 0; kk < 4; kk++) acc = MFMA16(ao[kk], pwf[nt2][kk], acc);
        int j = wid * 32 + nt2 * 16 + lr;
#pragma unroll
        for (int i = 0; i < 4; i++) {
          size_t off = (size_t)gidx[st][i] * 128 + j;
          out[off] = xres[st][nt2][i] + acc[i] + pb2[nt2];
        }
      }
    }
  }
}

// sigmoid-gelu: x * sigma(1.702x); |err| vs tanh-gelu < 0.005 for |x|<~1.5
__device__ __forceinline__ float gelu_sig(float x) {
  float e = exp2f(x * -2.4554826f);   // 1.702 * log2(e)
  return x * __builtin_amdgcn_rcpf(1.f + e);
}

__global__ __launch_bounds__(512, 4) void mlp_kernel(
    const float* __restrict__ ln2_w, const float* __restrict__ ln2_b,
    const float* __restrict__ mlp_b1, const float* __restrict__ mlp_b2,
    const unsigned char* __restrict__ ws, float* __restrict__ out) {
  __shared__ __attribute__((aligned(16))) __bf16 xn[64 * 128];  // LN2 out, swizzled (16 KB)
  __shared__ __attribute__((aligned(16))) __bf16 hb[64 * 256];  // gelu chunk; reused as f32 stage
  __shared__ __attribute__((aligned(16))) __bf16 x1b[64 * X1S]; // x1 stash bf16 (17.5 KB)
  const int tid = threadIdx.x;
  const int wid = tid >> 6, lane = tid & 63;
  const int lr = lane & 15, lk = lane >> 4;
  const f32x4 zero4 = {0.f, 0.f, 0.f, 0.f};
  const int row0 = blockIdx.x * 64;

  const __bf16* w1r = (const __bf16*)(ws + W1_OFF);
  const __bf16* w2r = (const __bf16*)(ws + W2_OFF);

  // NO persistent weight registers; only biases.
  float b1v[2][2];
#pragma unroll
  for (int c = 0; c < 2; c++)
#pragma unroll
    for (int nt = 0; nt < 2; nt++)
      b1v[c][nt] = mlp_b1[c * 256 + wid * 32 + nt * 16 + lr];
  float b2v = mlp_b2[wid * 16 + lr];

  // ---- LN2 (8 threads/row, 16 elems each) + x1 stash ----
  {
    int n = tid >> 3, q = tid & 7;
    const float4* xp = (const float4*)(out + (size_t)(row0 + n) * 128 + q * 16);
    float4 xv[4];
    float s = 0.f, s2 = 0.f;
#pragma unroll
    for (int t = 0; t < 4; t++) {
      float4 v = xp[t]; xv[t] = v;
      s += v.x + v.y + v.z + v.w;
      s2 += v.x * v.x + v.y * v.y + v.z * v.z + v.w * v.w;
    }
    s += __shfl_xor(s, 1); s += __shfl_xor(s, 2); s += __shfl_xor(s, 4);
    s2 += __shfl_xor(s2, 1); s2 += __shfl_xor(s2, 2); s2 += __shfl_xor(s2, 4);
    float mean = s * (1.f / 128.f);
    float var = s2 * (1.f / 128.f) - mean * mean;
    float rstd = rsqrtf(var + 1e-5f);
    const float4* wv = (const float4*)(ln2_w + q * 16);
    const float4* bv = (const float4*)(ln2_b + q * 16);
    bf16x8 o[2], r[2];
#pragma unroll
    for (int t = 0; t < 4; t++) {
      float4 wt = wv[t], bt = bv[t], v = xv[t];
      o[t >> 1][(t & 1) * 4 + 0] = (__bf16)((v.x - mean) * rstd * wt.x + bt.x);
      o[t >> 1][(t & 1) * 4 + 1] = (__bf16)((v.y - mean) * rstd * wt.y + bt.y);
      o[t >> 1][(t & 1) * 4 + 2] = (__bf16)((v.z - mean) * rstd * wt.z + bt.z);
      o[t >> 1][(t & 1) * 4 + 3] = (__bf16)((v.w - mean) * rstd * wt.w + bt.w);
      r[t >> 1][(t & 1) * 4 + 0] = (__bf16)v.x;
      r[t >> 1][(t & 1) * 4 + 1] = (__bf16)v.y;
      r[t >> 1][(t & 1) * 4 + 2] = (__bf16)v.z;
      r[t >> 1][(t & 1) * 4 + 3] = (__bf16)v.w;
    }
    *(bf16x8*)(xn + n * 128 + (((q * 2 + 0) ^ (n & 15)) << 3)) = o[0];
    *(bf16x8*)(xn + n * 128 + (((q * 2 + 1) ^ (n & 15)) << 3)) = o[1];
    *(bf16x8*)(x1b + n * X1S + q * 16) = r[0];
    *(bf16x8*)(x1b + n * X1S + q * 16 + 8) = r[1];
  }
  __syncthreads();

  f32x4 macc[4] = {zero4, zero4, zero4, zero4};

#pragma unroll 1
  for (int c = 0; c < 2; c++) {
    // ---- fc1 + gelu -> hb chunk; w1f live ONLY in this phase (32 VGPR) ----
    {
      bf16x8 w1f[2][4];
#pragma unroll
      for (int nt = 0; nt < 2; nt++)
#pragma unroll
        for (int kk = 0; kk < 4; kk++)
          w1f[nt][kk] = *(const bf16x8*)(w1r + (((c * 8 + wid) * 2 + nt) * 4 + kk) * 512 + lane * 8);
#pragma unroll
      for (int st = 0; st < 4; st++) {
        bf16x8 a1[4];
#pragma unroll
        for (int kk = 0; kk < 4; kk++)
          a1[kk] = *(const bf16x8*)(xn + (st * 16 + lr) * 128 + (((kk * 4 + lk) ^ lr) << 3));
#pragma unroll
        for (int nt = 0; nt < 2; nt++) {
          f32x4 acc = zero4;
#pragma unroll
          for (int kk = 0; kk < 4; kk++) acc = MFMA16(a1[kk], w1f[nt][kk], acc);
          int slot = wid * 4 + nt * 2 + (lr >> 3);
#pragma unroll
          for (int i = 0; i < 4; i++) {
            int row = st * 16 + lk * 4 + i;
            hb[row * 256 + ((slot ^ (row & 15)) << 3) + (lr & 7)] =
                (__bf16)gelu_sig(acc[i] + b1v[c][nt]);
          }
        }
      }
    }
    __syncthreads();

    // ---- fc2 partial; w2f live ONLY in this phase (32 VGPR) ----
    {
      bf16x8 w2f[8];
#pragma unroll
      for (int kks = 0; kks < 8; kks++)
        w2f[kks] = *(const bf16x8*)(w2r + (wid * 16 + c * 8 + kks) * 512 + lane * 8);
#pragma unroll
      for (int st = 0; st < 4; st++) {
#pragma unroll
        for (int kks = 0; kks < 8; kks++) {
          bf16x8 ah = *(const bf16x8*)(hb + (st * 16 + lr) * 256 + (((kks * 4 + lk) ^ lr) << 3));
          macc[st] = MFMA16(ah, w2f[kks], macc[st]);
        }
      }
    }
    __syncthreads();  // c0: protect hb overwrite by c1 fc1; c1: protect f32 staging
  }

  // ---- epilogue: stage x1+fc2+b2 (f32) in hb, then line-complete stores ----
  {
    float* stg = (float*)hb;  // 64 x 128 f32 = 32 KB exactly
#pragma unroll
    for (int st = 0; st < 4; st++)
#pragma unroll
      for (int i = 0; i < 4; i++) {
        int row = st * 16 + lk * 4 + i;
        int col = wid * 16 + lr;
        int sp = (col >> 2) ^ (((row >> 2) & 7) << 2);  // bijective slot swizzle per row
        float x1v = (float)x1b[row * X1S + col];
        stg[row * 128 + sp * 4 + (col & 3)] = x1v + macc[st][i] + b2v;
      }
    __syncthreads();
    // each wave stores rows wid*8..wid*8+7: 1 KB contiguous per iteration,
    // every 128B line written completely by one instruction (no partial-line miss)
    int half = lane >> 5, sl = lane & 31;
#pragma unroll
    for (int it = 0; it < 4; it++) {
      int row = wid * 8 + it * 2 + half;
      int sp = sl ^ (((row >> 2) & 7) << 2);
      f32x4 v = *(const f32x4*)(stg + row * 128 + sp * 4);
      *(f32x4*)(out + (size_t)(row0 + row) * 128 + sl * 4) = v;
    }
  }
}

extern "C" void kernel_launch(void* const* d_in, const int* in_sizes, int n_in,
                              void* d_out, int out_size, void* d_ws, size_t ws_size,
                              hipStream_t stream) {
  const float* x      = (const float*)d_in[0];
  const float* ln1_w  = (const float*)d_in[1];
  const float* ln1_b  = (const float*)d_in[2];
  const float* qkv_w  = (const float*)d_in[3];
  const float* qkv_b  = (const float*)d_in[4];
  const float* rel_b  = (const float*)d_in[5];
  const float* proj_w = (const float*)d_in[6];
  const float* proj_b = (const float*)d_in[7];
  const float* ln2_w  = (const float*)d_in[8];
  const float* ln2_b  = (const float*)d_in[9];
  const float* mlp_w1 = (const float*)d_in[10];
  const float* mlp_b1 = (const float*)d_in[11];
  const float* mlp_w2 = (const float*)d_in[12];
  const float* mlp_b2 = (const float*)d_in[13];
  float* out = (float*)d_out;
  unsigned char* ws = (unsigned char*)d_ws;

  prep_kernel<<<256, 256, 0, stream>>>(qkv_w, proj_w, mlp_w1, mlp_w2, rel_b, ws);
  attn_kernel<<<4096, 256, 0, stream>>>(x, ln1_w, ln1_b, qkv_b, proj_b, ws, out);
  mlp_kernel<<<4096, 512, 0, stream>>>(ln2_w, ln2_b, mlp_b1, mlp_b2, ws, out);
}

// Round 13
// 238.759 us; speedup vs baseline: 1.5448x; 1.0737x over previous
//
#include <hip/hip_runtime.h>
#include <hip/hip_bf16.h>

// FBANetLayer: Swin-style block. H=W=512, DIM=128, WL=8, SS=4, HEADS=4, HD=32.
// attn: head-per-wave; swapped-QK^T scores with bias C-init; max-free softmax;
//       wave-private LDS; residual prefetch; raw lgkm-only barriers. (FROZEN)
// mlp:  grid 4096 x 64 rows; hidden in 4 chunks of 128 (hb 16KB) -> LDS 50.2KB
//       -> 3 blocks/CU (24 waves, launch_bounds(512,6)); x1 stashed bf16
//       (PROVEN numerics -- r12's stats-reconstruction was lossy); biases in
//       MFMA C-init; disjoint per-chunk w1f/w2f (16 regs each, no spill);
//       epilogue staged f32 over dead xn+hb, line-complete 1KB/wave stores.

typedef __bf16 bf16x8 __attribute__((ext_vector_type(8)));
typedef __bf16 bf16x2 __attribute__((ext_vector_type(2)));
typedef float f32x4 __attribute__((ext_vector_type(4)));

#define MFMA16(a, b, c) __builtin_amdgcn_mfma_f32_16x16x32_bf16(a, b, c, 0, 0, 0)
#define LGKM_BARRIER() do { \
    asm volatile("s_waitcnt lgkmcnt(0)" ::: "memory"); \
    __builtin_amdgcn_s_barrier(); } while (0)

#define SS 4
#define XS 136   // attn LDS stride (bf16) for the 128-wide xn tile (2-way banks)
#define QKS 40   // stride for 32-wide q/k/O tiles (2-way banks)
#define PSS 72   // stride for 64-wide ps / vt tiles (2-way banks)
#define X1S 136  // mlp x1-stash stride

// ws byte offsets (total 458,752 B)
#define QKV_W_OFF 0        // 384x128 bf16 frag-order: ((h*6+nt)*4+kk)*512 + lane*8
#define PROJ_W_OFF 98304   // 128x128 bf16 frag-order: ((wid*2+nt2)*4+kk)*512 + lane*8
#define W1_OFF 131072      // 512x128 bf16 frag-order, 128-row groups: (g*4+kk)*512+lane*8, g=j>>4
#define W2_OFF 262144      // 128x512 bf16 frag-order: (wid*16+kk)*512 + lane*8 (plain k order)
#define BIAS_OFF 393216    // bias C-frag table: f32[((h*4+qt)*4+kt)*256 + lane*4 + i]

__device__ __forceinline__ int regid(int u) { return (u >= 508) ? 2 : ((u >= 504) ? 1 : 0); }

__global__ __launch_bounds__(256) void prep_kernel(
    const float* __restrict__ qkv_w, const float* __restrict__ proj_w,
    const float* __restrict__ w1, const float* __restrict__ w2,
    const float* __restrict__ rel_bias, unsigned char* __restrict__ ws) {
  int tid = blockIdx.x * 256 + threadIdx.x;
  __bf16* qw = (__bf16*)(ws + QKV_W_OFF);
  __bf16* pw = (__bf16*)(ws + PROJ_W_OFF);
  __bf16* w1b = (__bf16*)(ws + W1_OFF);
  __bf16* w2b = (__bf16*)(ws + W2_OFF);
  float* btbl = (float*)(ws + BIAS_OFF);
  if (tid < 49152) {
    int e = tid & 7, lane = (tid >> 3) & 63, kk = (tid >> 9) & 3;
    int f = tid >> 11;            // 0..23 = h*6+nt
    int h = f / 6, nt = f % 6;
    int j = (nt >> 1) * 128 + h * 32 + (nt & 1) * 16 + (lane & 15);
    int k = kk * 32 + (lane >> 4) * 8 + e;
    qw[tid] = (__bf16)qkv_w[j * 128 + k];
  }
  if (tid < 16384) {
    int e = tid & 7, lane = (tid >> 3) & 63, kk = (tid >> 9) & 3;
    int nt2 = (tid >> 11) & 1, wid = (tid >> 12) & 3;
    int j = wid * 32 + nt2 * 16 + (lane & 15);
    int k = kk * 32 + (lane >> 4) * 8 + e;
    pw[tid] = (__bf16)proj_w[j * 128 + k];
  }
  if (tid < 65536) {
    { // w1: 32 groups of 16 rows, frag (g*4+kk); g = c*8+wid for 128-col chunks
      int e = tid & 7, lane = (tid >> 3) & 63, kk = (tid >> 9) & 3;
      int g = (tid >> 11) & 31;
      int j = g * 16 + (lane & 15);
      int k = kk * 32 + (lane >> 4) * 8 + e;
      w1b[tid] = (__bf16)w1[j * 128 + k]; }
    { // w2: plain frag-linear k order (wid*16+kk)
      int e = tid & 7, lane = (tid >> 3) & 63, kk = (tid >> 9) & 15, wid = (tid >> 13) & 7;
      int j = wid * 16 + (lane & 15);
      int k = kk * 32 + (lane >> 4) * 8 + e;
      w2b[tid] = (__bf16)w2[j * 512 + k]; }
  }
  if (tid < 16384) {
    // bias C-frag table: lane holds C[row=k-tok=(l>>4)*4+i][col=q-tok=l&15]
    int i = tid & 3, lane = (tid >> 2) & 63;
    int kt = (tid >> 8) & 3, qt = (tid >> 10) & 3, h = (tid >> 12) & 3;
    int n = qt * 16 + (lane & 15);          // q token
    int m = kt * 16 + (lane >> 4) * 4 + i;  // k token
    int idx = ((n >> 3) - (m >> 3) + 7) * 15 + ((n & 7) - (m & 7) + 7);
    btbl[tid] = rel_bias[idx * 4 + h];
  }
}

__global__ __launch_bounds__(256, 2) void attn_kernel(
    const float* __restrict__ x, const float* __restrict__ ln1_w, const float* __restrict__ ln1_b,
    const float* __restrict__ qkv_b, const float* __restrict__ proj_b,
    const unsigned char* __restrict__ ws, float* __restrict__ out) {
  __shared__ __attribute__((aligned(16))) __bf16 xn[64 * XS];   // 17,408 B
  __shared__ __attribute__((aligned(16))) __bf16 wreg[4][5120]; // 4 x 10,240 B
  __shared__ __attribute__((aligned(16))) __bf16 vt[4][32 * PSS]; // 4 x 4,608 B
  __shared__ __attribute__((aligned(16))) int rid[64];

  const int w = blockIdx.x;
  const int wi = w >> 6, wj = w & 63;
  const int tid = threadIdx.x;
  const int wid = tid >> 6, lane = tid & 63;
  const int lr = lane & 15, lk = lane >> 4;
  const bool edge = (wi == 63) || (wj == 63);
  const f32x4 zero4 = {0.f, 0.f, 0.f, 0.f};

  // ---- Hoisted QKV B-frags: wave wid's head slice {Q_h,K_h,V_h} ----
  const __bf16* qw = (const __bf16*)(ws + QKV_W_OFF);
  bf16x8 bw[6][4];
  float qb[6];
#pragma unroll
  for (int nt = 0; nt < 6; nt++) {
    qb[nt] = qkv_b[(nt >> 1) * 128 + wid * 32 + (nt & 1) * 16 + lr];
#pragma unroll
    for (int kk = 0; kk < 4; kk++)
      bw[nt][kk] = *(const bf16x8*)(qw + ((wid * 6 + nt) * 4 + kk) * 512 + lane * 8);
  }

  // ---- Phase A: gather rolled rows + LN1 -> bf16 LDS ----
  {
    int n = tid >> 2, q = tid & 3;
    int r = n >> 3, c = n & 7;
    int io = (wi * 8 + r + SS) & 511;
    int jo = (wj * 8 + c + SS) & 511;
    size_t gid = (size_t)io * 512 + jo;
    const float4* xp = (const float4*)(x + gid * 128 + q * 32);
    float4 xv[8];
    float s = 0.f, s2 = 0.f;
#pragma unroll
    for (int t = 0; t < 8; t++) {
      float4 v = xp[t]; xv[t] = v;
      s += v.x + v.y + v.z + v.w;
      s2 += v.x * v.x + v.y * v.y + v.z * v.z + v.w * v.w;
    }
    s += __shfl_xor(s, 1); s += __shfl_xor(s, 2);
    s2 += __shfl_xor(s2, 1); s2 += __shfl_xor(s2, 2);
    float mean = s * (1.f / 128.f);
    float var = s2 * (1.f / 128.f) - mean * mean;
    float rstd = rsqrtf(var + 1e-5f);
    const float4* wv = (const float4*)(ln1_w + q * 32);
    const float4* bv = (const float4*)(ln1_b + q * 32);
    __bf16* dst = xn + n * XS + q * 32;
#pragma unroll
    for (int t = 0; t < 8; t++) {
      float4 wt = wv[t], bt = bv[t], v = xv[t];
      dst[t * 4 + 0] = (__bf16)((v.x - mean) * rstd * wt.x + bt.x);
      dst[t * 4 + 1] = (__bf16)((v.y - mean) * rstd * wt.y + bt.y);
      dst[t * 4 + 2] = (__bf16)((v.z - mean) * rstd * wt.z + bt.z);
      dst[t * 4 + 3] = (__bf16)((v.w - mean) * rstd * wt.w + bt.w);
    }
    if (q == 0) rid[n] = 3 * regid(wi * 8 + r) + regid(wj * 8 + c);
  }
  LGKM_BARRIER();   // keep hoisted bw loads in flight (no vmcnt drain)

  // ---- Phase B: QKV for head wid (64 rows x 96 cols), into private LDS ----
  {
    const float scale = 0.17677669529663687f;  // 32^-0.5 folded into Q
    __bf16* qbase = &wreg[wid][0];
    __bf16* kbase = &wreg[wid][2560];
    __bf16* vbase = &vt[wid][0];
#pragma unroll
    for (int st = 0; st < 4; st++) {
      bf16x8 a[4];
#pragma unroll
      for (int kk = 0; kk < 4; kk++)
        a[kk] = *(const bf16x8*)(xn + (st * 16 + lr) * XS + kk * 32 + lk * 8);
#pragma unroll
      for (int nt = 0; nt < 6; nt++) {
        f32x4 acc = zero4;
#pragma unroll
        for (int kk = 0; kk < 4; kk++) acc = MFMA16(a[kk], bw[nt][kk], acc);
        float bias = qb[nt];
        int dl = (nt & 1) * 16 + lr;           // d_local within head
        if (nt < 2) {
#pragma unroll
          for (int i = 0; i < 4; i++)
            qbase[(st * 16 + lk * 4 + i) * QKS + dl] = (__bf16)((acc[i] + bias) * scale);
        } else if (nt < 4) {
#pragma unroll
          for (int i = 0; i < 4; i++)
            kbase[(st * 16 + lk * 4 + i) * QKS + dl] = (__bf16)(acc[i] + bias);
        } else {
#pragma unroll
          for (int i = 0; i < 4; i++)
            vbase[dl * PSS + st * 16 + lk * 4 + i] = (__bf16)(acc[i] + bias);
        }
      }
    }
  }

  // ---- hoist proj B-frags + bias C-frags (loads overlap frag staging) ----
  const __bf16* pw = (const __bf16*)(ws + PROJ_W_OFF);
  bf16x8 pwf[2][4];
  float pb2[2];
#pragma unroll
  for (int nt2 = 0; nt2 < 2; nt2++) {
    pb2[nt2] = proj_b[wid * 32 + nt2 * 16 + lr];
#pragma unroll
    for (int kk = 0; kk < 4; kk++)
      pwf[nt2][kk] = *(const bf16x8*)(pw + ((wid * 2 + nt2) * 4 + kk) * 512 + lane * 8);
  }
  const float* btbl = (const float*)(ws + BIAS_OFF);
  f32x4 bc[4][4];
#pragma unroll
  for (int qt = 0; qt < 4; qt++)
#pragma unroll
    for (int kt = 0; kt < 4; kt++)
      bc[qt][kt] = *(const f32x4*)(btbl + ((wid * 4 + qt) * 4 + kt) * 256 + lane * 4);

  // ---- prefetch residual x for phase D (latency hides under phase C) ----
  int gidx[4][4];
#pragma unroll
  for (int st = 0; st < 4; st++)
#pragma unroll
    for (int i = 0; i < 4; i++) {
      int rr = st * 16 + lk * 4 + i;
      int io = (wi * 8 + (rr >> 3) + SS) & 511;
      int jo = (wj * 8 + (rr & 7) + SS) & 511;
      gidx[st][i] = io * 512 + jo;
    }
  float xres[4][2][4];
#pragma unroll
  for (int st = 0; st < 4; st++)
#pragma unroll
    for (int nt2 = 0; nt2 < 2; nt2++)
#pragma unroll
      for (int i = 0; i < 4; i++)
        xres[st][nt2][i] = x[(size_t)gidx[st][i] * 128 + wid * 32 + nt2 * 16 + lr];

  // ---- Phase C: head-private attention (no barriers) ----
  {
    __bf16* reg0 = &wreg[wid][0];
    bf16x8 kf[4], qf[4], vf[2][2];
#pragma unroll
    for (int kt = 0; kt < 4; kt++)
      kf[kt] = *(const bf16x8*)(reg0 + 2560 + (kt * 16 + lr) * QKS + lk * 8);
#pragma unroll
    for (int qt = 0; qt < 4; qt++)
      qf[qt] = *(const bf16x8*)(reg0 + (qt * 16 + lr) * QKS + lk * 8);
#pragma unroll
    for (int dt = 0; dt < 2; dt++)
#pragma unroll
      for (int kk = 0; kk < 2; kk++)
        vf[dt][kk] = *(const bf16x8*)(&vt[wid][(dt * 16 + lr) * PSS + kk * 32 + lk * 8]);
    // ensure frag reads retired before overwriting region with ps
    asm volatile("s_waitcnt lgkmcnt(0)" ::: "memory");
    __builtin_amdgcn_sched_barrier(0);

    int4 rk[4];
    if (edge) {
#pragma unroll
      for (int kt = 0; kt < 4; kt++) rk[kt] = *(const int4*)&rid[kt * 16 + lk * 4];
    }

#pragma unroll
    for (int qt = 0; qt < 4; qt++) {
      f32x4 s[4];
#pragma unroll
      for (int kt = 0; kt < 4; kt++) s[kt] = MFMA16(kf[kt], qf[qt], bc[qt][kt]);
      if (edge) {
        int rq = rid[qt * 16 + lr];
#pragma unroll
        for (int kt = 0; kt < 4; kt++) {
          s[kt][0] += (rk[kt].x != rq) ? -100.f : 0.f;
          s[kt][1] += (rk[kt].y != rq) ? -100.f : 0.f;
          s[kt][2] += (rk[kt].z != rq) ? -100.f : 0.f;
          s[kt][3] += (rk[kt].w != rq) ? -100.f : 0.f;
        }
      }
      float ex[4][4];
      float sum = 0.f;
#pragma unroll
      for (int kt = 0; kt < 4; kt++) {
#pragma unroll
        for (int i = 0; i < 4; i++) { ex[kt][i] = __expf(s[kt][i]); sum += ex[kt][i]; }
      }
      sum += __shfl_xor(sum, 16);
      sum += __shfl_xor(sum, 32);
      float inv = __builtin_amdgcn_rcpf(sum);
      __bf16* psrow = reg0 + (qt * 16 + lr) * PSS;
#pragma unroll
      for (int kt = 0; kt < 4; kt++) {
        bf16x2 p01 = {(__bf16)(ex[kt][0] * inv), (__bf16)(ex[kt][1] * inv)};
        bf16x2 p23 = {(__bf16)(ex[kt][2] * inv), (__bf16)(ex[kt][3] * inv)};
        *(bf16x2*)(psrow + kt * 16 + lk * 4) = p01;
        *(bf16x2*)(psrow + kt * 16 + lk * 4 + 2) = p23;
      }
#pragma unroll
      for (int dt = 0; dt < 2; dt++) {
        bf16x8 pa0 = *(const bf16x8*)(reg0 + (qt * 16 + lr) * PSS + lk * 8);
        bf16x8 pa1 = *(const bf16x8*)(reg0 + (qt * 16 + lr) * PSS + 32 + lk * 8);
        f32x4 acc = MFMA16(pa0, vf[dt][0], zero4);
        acc = MFMA16(pa1, vf[dt][1], acc);
#pragma unroll
        for (int i = 0; i < 4; i++)
          reg0[qt * 1152 + (lk * 4 + i) * QKS + dt * 16 + lr] = (__bf16)acc[i];
      }
    }
  }
  LGKM_BARRIER();   // keep xres prefetch in flight (no vmcnt drain)

  // ---- Phase D: proj col-slice (wave owns 32 cols) + residual, inverse roll ----
  {
#pragma unroll
    for (int st = 0; st < 4; st++) {
      bf16x8 ao[4];
#pragma unroll
      for (int kk = 0; kk < 4; kk++)   // head kk's O stripe st
        ao[kk] = *(const bf16x8*)(&wreg[kk][st * 1152 + lr * QKS + lk * 8]);
#pragma unroll
      for (int nt2 = 0; nt2 < 2; nt2++) {
        f32x4 acc = zero4;
#pragma unroll
        for (int kk = 0; kk < 4; kk++) acc = MFMA16(ao[kk], pwf[nt2][kk], acc);
        int j = wid * 32 + nt2 * 16 + lr;
#pragma unroll
        for (int i = 0; i < 4; i++) {
          size_t off = (size_t)gidx[st][i] * 128 + j;
          out[off] = xres[st][nt2][i] + acc[i] + pb2[nt2];
        }
      }
    }
  }
}

// sigmoid-gelu: x * sigma(1.702x); |err| vs tanh-gelu < 0.005 for |x|<~1.5
__device__ __forceinline__ float gelu_sig(float x) {
  float e = exp2f(x * -2.4554826f);   // 1.702 * log2(e)
  return x * __builtin_amdgcn_rcpf(1.f + e);
}

__global__ __launch_bounds__(512, 6) void mlp_kernel(
    const float* __restrict__ ln2_w, const float* __restrict__ ln2_b,
    const float* __restrict__ mlp_b1, const float* __restrict__ mlp_b2,
    const unsigned char* __restrict__ ws, float* __restrict__ out) {
  // manual LDS layout: xn 16KB | hb 16KB | x1b 17KB = 50,176 B total.
  // epilogue reuses [0,32KB) (dead xn+hb) as the f32 staging tile.
  __shared__ __attribute__((aligned(16))) unsigned char smem[50176];
  __bf16* xn  = (__bf16*)smem;            // 64 x 128, XOR-swizzled
  __bf16* hb  = (__bf16*)(smem + 16384);  // 64 x 128 chunk, XOR-swizzled
  __bf16* x1b = (__bf16*)(smem + 32768);  // 64 x X1S bf16 stash
  const int tid = threadIdx.x;
  const int wid = tid >> 6, lane = tid & 63;
  const int lr = lane & 15, lk = lane >> 4;
  const int row0 = blockIdx.x * 64;
  const int col = wid * 16 + lr;   // this lane's output column

  const __bf16* w1r = (const __bf16*)(ws + W1_OFF);
  const __bf16* w2r = (const __bf16*)(ws + W2_OFF);

  // per-lane constants (biases folded into MFMA C-init)
  float b1v[4];
#pragma unroll
  for (int c = 0; c < 4; c++) b1v[c] = mlp_b1[c * 128 + wid * 16 + lr];
  float b2v = mlp_b2[col];

  // ---- LN2 (8 threads/row, 16 elems each) + x1 bf16 stash ----
  {
    int n = tid >> 3, q = tid & 7;
    const float4* xp = (const float4*)(out + (size_t)(row0 + n) * 128 + q * 16);
    float4 xv[4];
    float s = 0.f, s2 = 0.f;
#pragma unroll
    for (int t = 0; t < 4; t++) {
      float4 v = xp[t]; xv[t] = v;
      s += v.x + v.y + v.z + v.w;
      s2 += v.x * v.x + v.y * v.y + v.z * v.z + v.w * v.w;
    }
    s += __shfl_xor(s, 1); s += __shfl_xor(s, 2); s += __shfl_xor(s, 4);
    s2 += __shfl_xor(s2, 1); s2 += __shfl_xor(s2, 2); s2 += __shfl_xor(s2, 4);
    float mean = s * (1.f / 128.f);
    float var = s2 * (1.f / 128.f) - mean * mean;
    float rstd = rsqrtf(var + 1e-5f);
    const float4* wv = (const float4*)(ln2_w + q * 16);
    const float4* bv = (const float4*)(ln2_b + q * 16);
    bf16x8 o[2], r[2];
#pragma unroll
    for (int t = 0; t < 4; t++) {
      float4 wt = wv[t], bt = bv[t], v = xv[t];
      o[t >> 1][(t & 1) * 4 + 0] = (__bf16)((v.x - mean) * rstd * wt.x + bt.x);
      o[t >> 1][(t & 1) * 4 + 1] = (__bf16)((v.y - mean) * rstd * wt.y + bt.y);
      o[t >> 1][(t & 1) * 4 + 2] = (__bf16)((v.z - mean) * rstd * wt.z + bt.z);
      o[t >> 1][(t & 1) * 4 + 3] = (__bf16)((v.w - mean) * rstd * wt.w + bt.w);
      r[t >> 1][(t & 1) * 4 + 0] = (__bf16)v.x;
      r[t >> 1][(t & 1) * 4 + 1] = (__bf16)v.y;
      r[t >> 1][(t & 1) * 4 + 2] = (__bf16)v.z;
      r[t >> 1][(t & 1) * 4 + 3] = (__bf16)v.w;
    }
    *(bf16x8*)(xn + n * 128 + (((q * 2 + 0) ^ (n & 15)) << 3)) = o[0];
    *(bf16x8*)(xn + n * 128 + (((q * 2 + 1) ^ (n & 15)) << 3)) = o[1];
    *(bf16x8*)(x1b + n * X1S + q * 16) = r[0];
    *(bf16x8*)(x1b + n * X1S + q * 16 + 8) = r[1];
  }
  __syncthreads();

  f32x4 macc[4];
#pragma unroll
  for (int st = 0; st < 4; st++) macc[st] = (f32x4){b2v, b2v, b2v, b2v};

#pragma unroll 1
  for (int c = 0; c < 4; c++) {
    // ---- fc1 + gelu -> hb chunk (128 hidden); w1f live only here (16 VGPR) ----
    {
      bf16x8 w1f[4];
#pragma unroll
      for (int kk = 0; kk < 4; kk++)
        w1f[kk] = *(const bf16x8*)(w1r + ((c * 8 + wid) * 4 + kk) * 512 + lane * 8);
      f32x4 bini = {b1v[c], b1v[c], b1v[c], b1v[c]};
      int slot = wid * 2 + (lr >> 3);
#pragma unroll
      for (int st = 0; st < 4; st++) {
        bf16x8 a1[4];
#pragma unroll
        for (int kk = 0; kk < 4; kk++)
          a1[kk] = *(const bf16x8*)(xn + (st * 16 + lr) * 128 + (((kk * 4 + lk) ^ lr) << 3));
        f32x4 acc = bini;
#pragma unroll
        for (int kk = 0; kk < 4; kk++) acc = MFMA16(a1[kk], w1f[kk], acc);
#pragma unroll
        for (int i = 0; i < 4; i++) {
          int row = st * 16 + lk * 4 + i;
          hb[row * 128 + ((slot ^ (row & 15)) << 3) + (lr & 7)] =
              (__bf16)gelu_sig(acc[i]);
        }
      }
    }
    __syncthreads();

    // ---- fc2 partial over this chunk's K=128; w2f live only here (16 VGPR) ----
    {
      bf16x8 w2f[4];
#pragma unroll
      for (int kks = 0; kks < 4; kks++)
        w2f[kks] = *(const bf16x8*)(w2r + (wid * 16 + c * 4 + kks) * 512 + lane * 8);
#pragma unroll
      for (int st = 0; st < 4; st++) {
#pragma unroll
        for (int kks = 0; kks < 4; kks++) {
          bf16x8 ah = *(const bf16x8*)(hb + (st * 16 + lr) * 128 + (((kks * 4 + lk) ^ lr) << 3));
          macc[st] = MFMA16(ah, w2f[kks], macc[st]);
        }
      }
    }
    __syncthreads();  // protect hb overwrite by next fc1 / f32 staging
  }

  // ---- epilogue: stage x1(stash)+fc2+b2 (f32) over dead xn+hb, line-complete stores ----
  {
    float* stg = (float*)smem;  // 64 x 128 f32 = 32 KB (xn+hb region, both dead)
#pragma unroll
    for (int st = 0; st < 4; st++)
#pragma unroll
      for (int i = 0; i < 4; i++) {
        int row = st * 16 + lk * 4 + i;
        float x1v = (float)x1b[row * X1S + col];
        int sp = (col >> 2) ^ (((row >> 2) & 7) << 2);  // bijective slot swizzle per row
        stg[row * 128 + sp * 4 + (col & 3)] = x1v + macc[st][i];
      }
    __syncthreads();
    // each wave stores rows wid*8..wid*8+7: 1 KB contiguous per iteration,
    // every 128B line written completely by one instruction (no partial-line miss)
    int half = lane >> 5, sl = lane & 31;
#pragma unroll
    for (int it = 0; it < 4; it++) {
      int row = wid * 8 + it * 2 + half;
      int sp = sl ^ (((row >> 2) & 7) << 2);
      f32x4 v = *(const f32x4*)(stg + row * 128 + sp * 4);
      *(f32x4*)(out + (size_t)(row0 + row) * 128 + sl * 4) = v;
    }
  }
}

extern "C" void kernel_launch(void* const* d_in, const int* in_sizes, int n_in,
                              void* d_out, int out_size, void* d_ws, size_t ws_size,
                              hipStream_t stream) {
  const float* x      = (const float*)d_in[0];
  const float* ln1_w  = (const float*)d_in[1];
  const float* ln1_b  = (const float*)d_in[2];
  const float* qkv_w  = (const float*)d_in[3];
  const float* qkv_b  = (const float*)d_in[4];
  const float* rel_b  = (const float*)d_in[5];
  const float* proj_w = (const float*)d_in[6];
  const float* proj_b = (const float*)d_in[7];
  const float* ln2_w  = (const float*)d_in[8];
  const float* ln2_b  = (const float*)d_in[9];
  const float* mlp_w1 = (const float*)d_in[10];
  const float* mlp_b1 = (const float*)d_in[11];
  const float* mlp_w2 = (const float*)d_in[12];
  const float* mlp_b2 = (const float*)d_in[13];
  float* out = (float*)d_out;
  unsigned char* ws = (unsigned char*)d_ws;

  prep_kernel<<<256, 256, 0, stream>>>(qkv_w, proj_w, mlp_w1, mlp_w2, rel_b, ws);
  attn_kernel<<<4096, 256, 0, stream>>>(x, ln1_w, ln1_b, qkv_b, proj_b, ws, out);
  mlp_kernel<<<4096, 512, 0, stream>>>(ln2_w, ln2_b, mlp_b1, mlp_b2, ws, out);
}

// Round 14
// 234.863 us; speedup vs baseline: 1.5704x; 1.0166x over previous
//
#include <hip/hip_runtime.h>
#include <hip/hip_bf16.h>

// FBANetLayer: Swin-style block. H=W=512, DIM=128, WL=8, SS=4, HEADS=4, HD=32.
// attn: head-per-wave; swapped-QK^T scores with bias C-init; max-free softmax;
//       wave-private LDS; residual prefetch; raw lgkm-only barriers; setprio
//       around phase-C MFMA clusters (T5).
// mlp:  grid 4096 x 64 rows; 4 hidden chunks of 128; SWAPPED fc1 (C rows =
//       hidden) so gelu outputs pack into ds_write_b64 (64 scalar stores ->
//       16); biases exact f32 C-init; lgkm-only barriers; w2f issued before
//       the post-fc1 barrier; x1 stashed bf16; staged line-complete stores.

typedef __bf16 bf16x8 __attribute__((ext_vector_type(8)));
typedef __bf16 bf16x4 __attribute__((ext_vector_type(4)));
typedef __bf16 bf16x2 __attribute__((ext_vector_type(2)));
typedef float f32x4 __attribute__((ext_vector_type(4)));

#define MFMA16(a, b, c) __builtin_amdgcn_mfma_f32_16x16x32_bf16(a, b, c, 0, 0, 0)
#define LGKM_BARRIER() do { \
    asm volatile("s_waitcnt lgkmcnt(0)" ::: "memory"); \
    __builtin_amdgcn_s_barrier(); } while (0)

#define SS 4
#define XS 136   // attn LDS stride (bf16) for the 128-wide xn tile (2-way banks)
#define QKS 40   // stride for 32-wide q/k/O tiles (2-way banks)
#define PSS 72   // stride for 64-wide ps / vt tiles (2-way banks)
#define X1S 136  // mlp x1-stash stride

// ws byte offsets (total 458,752 B)
#define QKV_W_OFF 0        // 384x128 bf16 frag-order: ((h*6+nt)*4+kk)*512 + lane*8
#define PROJ_W_OFF 98304   // 128x128 bf16 frag-order: ((wid*2+nt2)*4+kk)*512 + lane*8
#define W1_OFF 131072      // 512x128 bf16 frag-order, 16-row groups: (g*4+kk)*512+lane*8
#define W2_OFF 262144      // 128x512 bf16 frag-order: (wid*16+kk)*512 + lane*8
#define BIAS_OFF 393216    // bias C-frag table: f32[((h*4+qt)*4+kt)*256 + lane*4 + i]

__device__ __forceinline__ int regid(int u) { return (u >= 508) ? 2 : ((u >= 504) ? 1 : 0); }

__global__ __launch_bounds__(256) void prep_kernel(
    const float* __restrict__ qkv_w, const float* __restrict__ proj_w,
    const float* __restrict__ w1, const float* __restrict__ w2,
    const float* __restrict__ rel_bias, unsigned char* __restrict__ ws) {
  int tid = blockIdx.x * 256 + threadIdx.x;
  __bf16* qw = (__bf16*)(ws + QKV_W_OFF);
  __bf16* pw = (__bf16*)(ws + PROJ_W_OFF);
  __bf16* w1b = (__bf16*)(ws + W1_OFF);
  __bf16* w2b = (__bf16*)(ws + W2_OFF);
  float* btbl = (float*)(ws + BIAS_OFF);
  if (tid < 49152) {
    int e = tid & 7, lane = (tid >> 3) & 63, kk = (tid >> 9) & 3;
    int f = tid >> 11;            // 0..23 = h*6+nt
    int h = f / 6, nt = f % 6;
    int j = (nt >> 1) * 128 + h * 32 + (nt & 1) * 16 + (lane & 15);
    int k = kk * 32 + (lane >> 4) * 8 + e;
    qw[tid] = (__bf16)qkv_w[j * 128 + k];
  }
  if (tid < 16384) {
    int e = tid & 7, lane = (tid >> 3) & 63, kk = (tid >> 9) & 3;
    int nt2 = (tid >> 11) & 1, wid = (tid >> 12) & 3;
    int j = wid * 32 + nt2 * 16 + (lane & 15);
    int k = kk * 32 + (lane >> 4) * 8 + e;
    pw[tid] = (__bf16)proj_w[j * 128 + k];
  }
  if (tid < 65536) {
    { // w1: 32 groups of 16 rows, frag (g*4+kk); g = c*8+wid for 128-col chunks
      int e = tid & 7, lane = (tid >> 3) & 63, kk = (tid >> 9) & 3;
      int g = (tid >> 11) & 31;
      int j = g * 16 + (lane & 15);
      int k = kk * 32 + (lane >> 4) * 8 + e;
      w1b[tid] = (__bf16)w1[j * 128 + k]; }
    { // w2: plain frag-linear k order (wid*16+kk)
      int e = tid & 7, lane = (tid >> 3) & 63, kk = (tid >> 9) & 15, wid = (tid >> 13) & 7;
      int j = wid * 16 + (lane & 15);
      int k = kk * 32 + (lane >> 4) * 8 + e;
      w2b[tid] = (__bf16)w2[j * 512 + k]; }
  }
  if (tid < 16384) {
    // bias C-frag table: lane holds C[row=k-tok=(l>>4)*4+i][col=q-tok=l&15]
    int i = tid & 3, lane = (tid >> 2) & 63;
    int kt = (tid >> 8) & 3, qt = (tid >> 10) & 3, h = (tid >> 12) & 3;
    int n = qt * 16 + (lane & 15);          // q token
    int m = kt * 16 + (lane >> 4) * 4 + i;  // k token
    int idx = ((n >> 3) - (m >> 3) + 7) * 15 + ((n & 7) - (m & 7) + 7);
    btbl[tid] = rel_bias[idx * 4 + h];
  }
}

__global__ __launch_bounds__(256, 2) void attn_kernel(
    const float* __restrict__ x, const float* __restrict__ ln1_w, const float* __restrict__ ln1_b,
    const float* __restrict__ qkv_b, const float* __restrict__ proj_b,
    const unsigned char* __restrict__ ws, float* __restrict__ out) {
  __shared__ __attribute__((aligned(16))) __bf16 xn[64 * XS];   // 17,408 B
  __shared__ __attribute__((aligned(16))) __bf16 wreg[4][5120]; // 4 x 10,240 B
  __shared__ __attribute__((aligned(16))) __bf16 vt[4][32 * PSS]; // 4 x 4,608 B
  __shared__ __attribute__((aligned(16))) int rid[64];

  const int w = blockIdx.x;
  const int wi = w >> 6, wj = w & 63;
  const int tid = threadIdx.x;
  const int wid = tid >> 6, lane = tid & 63;
  const int lr = lane & 15, lk = lane >> 4;
  const bool edge = (wi == 63) || (wj == 63);
  const f32x4 zero4 = {0.f, 0.f, 0.f, 0.f};

  // ---- Hoisted QKV B-frags: wave wid's head slice {Q_h,K_h,V_h} ----
  const __bf16* qw = (const __bf16*)(ws + QKV_W_OFF);
  bf16x8 bw[6][4];
  float qb[6];
#pragma unroll
  for (int nt = 0; nt < 6; nt++) {
    qb[nt] = qkv_b[(nt >> 1) * 128 + wid * 32 + (nt & 1) * 16 + lr];
#pragma unroll
    for (int kk = 0; kk < 4; kk++)
      bw[nt][kk] = *(const bf16x8*)(qw + ((wid * 6 + nt) * 4 + kk) * 512 + lane * 8);
  }

  // ---- Phase A: gather rolled rows + LN1 -> bf16 LDS ----
  {
    int n = tid >> 2, q = tid & 3;
    int r = n >> 3, c = n & 7;
    int io = (wi * 8 + r + SS) & 511;
    int jo = (wj * 8 + c + SS) & 511;
    size_t gid = (size_t)io * 512 + jo;
    const float4* xp = (const float4*)(x + gid * 128 + q * 32);
    float4 xv[8];
    float s = 0.f, s2 = 0.f;
#pragma unroll
    for (int t = 0; t < 8; t++) {
      float4 v = xp[t]; xv[t] = v;
      s += v.x + v.y + v.z + v.w;
      s2 += v.x * v.x + v.y * v.y + v.z * v.z + v.w * v.w;
    }
    s += __shfl_xor(s, 1); s += __shfl_xor(s, 2);
    s2 += __shfl_xor(s2, 1); s2 += __shfl_xor(s2, 2);
    float mean = s * (1.f / 128.f);
    float var = s2 * (1.f / 128.f) - mean * mean;
    float rstd = rsqrtf(var + 1e-5f);
    const float4* wv = (const float4*)(ln1_w + q * 32);
    const float4* bv = (const float4*)(ln1_b + q * 32);
    __bf16* dst = xn + n * XS + q * 32;
#pragma unroll
    for (int t = 0; t < 8; t++) {
      float4 wt = wv[t], bt = bv[t], v = xv[t];
      dst[t * 4 + 0] = (__bf16)((v.x - mean) * rstd * wt.x + bt.x);
      dst[t * 4 + 1] = (__bf16)((v.y - mean) * rstd * wt.y + bt.y);
      dst[t * 4 + 2] = (__bf16)((v.z - mean) * rstd * wt.z + bt.z);
      dst[t * 4 + 3] = (__bf16)((v.w - mean) * rstd * wt.w + bt.w);
    }
    if (q == 0) rid[n] = 3 * regid(wi * 8 + r) + regid(wj * 8 + c);
  }
  LGKM_BARRIER();   // keep hoisted bw loads in flight (no vmcnt drain)

  // ---- Phase B: QKV for head wid (64 rows x 96 cols), into private LDS ----
  {
    const float scale = 0.17677669529663687f;  // 32^-0.5 folded into Q
    __bf16* qbase = &wreg[wid][0];
    __bf16* kbase = &wreg[wid][2560];
    __bf16* vbase = &vt[wid][0];
#pragma unroll
    for (int st = 0; st < 4; st++) {
      bf16x8 a[4];
#pragma unroll
      for (int kk = 0; kk < 4; kk++)
        a[kk] = *(const bf16x8*)(xn + (st * 16 + lr) * XS + kk * 32 + lk * 8);
#pragma unroll
      for (int nt = 0; nt < 6; nt++) {
        f32x4 acc = zero4;
#pragma unroll
        for (int kk = 0; kk < 4; kk++) acc = MFMA16(a[kk], bw[nt][kk], acc);
        float bias = qb[nt];
        int dl = (nt & 1) * 16 + lr;           // d_local within head
        if (nt < 2) {
#pragma unroll
          for (int i = 0; i < 4; i++)
            qbase[(st * 16 + lk * 4 + i) * QKS + dl] = (__bf16)((acc[i] + bias) * scale);
        } else if (nt < 4) {
#pragma unroll
          for (int i = 0; i < 4; i++)
            kbase[(st * 16 + lk * 4 + i) * QKS + dl] = (__bf16)(acc[i] + bias);
        } else {
#pragma unroll
          for (int i = 0; i < 4; i++)
            vbase[dl * PSS + st * 16 + lk * 4 + i] = (__bf16)(acc[i] + bias);
        }
      }
    }
  }

  // ---- hoist proj B-frags + bias C-frags (loads overlap frag staging) ----
  const __bf16* pw = (const __bf16*)(ws + PROJ_W_OFF);
  bf16x8 pwf[2][4];
  float pb2[2];
#pragma unroll
  for (int nt2 = 0; nt2 < 2; nt2++) {
    pb2[nt2] = proj_b[wid * 32 + nt2 * 16 + lr];
#pragma unroll
    for (int kk = 0; kk < 4; kk++)
      pwf[nt2][kk] = *(const bf16x8*)(pw + ((wid * 2 + nt2) * 4 + kk) * 512 + lane * 8);
  }
  const float* btbl = (const float*)(ws + BIAS_OFF);
  f32x4 bc[4][4];
#pragma unroll
  for (int qt = 0; qt < 4; qt++)
#pragma unroll
    for (int kt = 0; kt < 4; kt++)
      bc[qt][kt] = *(const f32x4*)(btbl + ((wid * 4 + qt) * 4 + kt) * 256 + lane * 4);

  // ---- prefetch residual x for phase D (latency hides under phase C) ----
  int gidx[4][4];
#pragma unroll
  for (int st = 0; st < 4; st++)
#pragma unroll
    for (int i = 0; i < 4; i++) {
      int rr = st * 16 + lk * 4 + i;
      int io = (wi * 8 + (rr >> 3) + SS) & 511;
      int jo = (wj * 8 + (rr & 7) + SS) & 511;
      gidx[st][i] = io * 512 + jo;
    }
  float xres[4][2][4];
#pragma unroll
  for (int st = 0; st < 4; st++)
#pragma unroll
    for (int nt2 = 0; nt2 < 2; nt2++)
#pragma unroll
      for (int i = 0; i < 4; i++)
        xres[st][nt2][i] = x[(size_t)gidx[st][i] * 128 + wid * 32 + nt2 * 16 + lr];

  // ---- Phase C: head-private attention (no barriers) ----
  {
    __bf16* reg0 = &wreg[wid][0];
    bf16x8 kf[4], qf[4], vf[2][2];
#pragma unroll
    for (int kt = 0; kt < 4; kt++)
      kf[kt] = *(const bf16x8*)(reg0 + 2560 + (kt * 16 + lr) * QKS + lk * 8);
#pragma unroll
    for (int qt = 0; qt < 4; qt++)
      qf[qt] = *(const bf16x8*)(reg0 + (qt * 16 + lr) * QKS + lk * 8);
#pragma unroll
    for (int dt = 0; dt < 2; dt++)
#pragma unroll
      for (int kk = 0; kk < 2; kk++)
        vf[dt][kk] = *(const bf16x8*)(&vt[wid][(dt * 16 + lr) * PSS + kk * 32 + lk * 8]);
    // ensure frag reads retired before overwriting region with ps
    asm volatile("s_waitcnt lgkmcnt(0)" ::: "memory");
    __builtin_amdgcn_sched_barrier(0);

    int4 rk[4];
    if (edge) {
#pragma unroll
      for (int kt = 0; kt < 4; kt++) rk[kt] = *(const int4*)&rid[kt * 16 + lk * 4];
    }

#pragma unroll
    for (int qt = 0; qt < 4; qt++) {
      f32x4 s[4];
      __builtin_amdgcn_s_setprio(1);
#pragma unroll
      for (int kt = 0; kt < 4; kt++) s[kt] = MFMA16(kf[kt], qf[qt], bc[qt][kt]);
      __builtin_amdgcn_s_setprio(0);
      if (edge) {
        int rq = rid[qt * 16 + lr];
#pragma unroll
        for (int kt = 0; kt < 4; kt++) {
          s[kt][0] += (rk[kt].x != rq) ? -100.f : 0.f;
          s[kt][1] += (rk[kt].y != rq) ? -100.f : 0.f;
          s[kt][2] += (rk[kt].z != rq) ? -100.f : 0.f;
          s[kt][3] += (rk[kt].w != rq) ? -100.f : 0.f;
        }
      }
      float ex[4][4];
      float sum = 0.f;
#pragma unroll
      for (int kt = 0; kt < 4; kt++) {
#pragma unroll
        for (int i = 0; i < 4; i++) { ex[kt][i] = __expf(s[kt][i]); sum += ex[kt][i]; }
      }
      sum += __shfl_xor(sum, 16);
      sum += __shfl_xor(sum, 32);
      float inv = __builtin_amdgcn_rcpf(sum);
      __bf16* psrow = reg0 + (qt * 16 + lr) * PSS;
#pragma unroll
      for (int kt = 0; kt < 4; kt++) {
        bf16x2 p01 = {(__bf16)(ex[kt][0] * inv), (__bf16)(ex[kt][1] * inv)};
        bf16x2 p23 = {(__bf16)(ex[kt][2] * inv), (__bf16)(ex[kt][3] * inv)};
        *(bf16x2*)(psrow + kt * 16 + lk * 4) = p01;
        *(bf16x2*)(psrow + kt * 16 + lk * 4 + 2) = p23;
      }
#pragma unroll
      for (int dt = 0; dt < 2; dt++) {
        bf16x8 pa0 = *(const bf16x8*)(reg0 + (qt * 16 + lr) * PSS + lk * 8);
        bf16x8 pa1 = *(const bf16x8*)(reg0 + (qt * 16 + lr) * PSS + 32 + lk * 8);
        __builtin_amdgcn_s_setprio(1);
        f32x4 acc = MFMA16(pa0, vf[dt][0], zero4);
        acc = MFMA16(pa1, vf[dt][1], acc);
        __builtin_amdgcn_s_setprio(0);
#pragma unroll
        for (int i = 0; i < 4; i++)
          reg0[qt * 1152 + (lk * 4 + i) * QKS + dt * 16 + lr] = (__bf16)acc[i];
      }
    }
  }
  LGKM_BARRIER();   // keep xres prefetch in flight (no vmcnt drain)

  // ---- Phase D: proj col-slice (wave owns 32 cols) + residual, inverse roll ----
  {
#pragma unroll
    for (int st = 0; st < 4; st++) {
      bf16x8 ao[4];
#pragma unroll
      for (int kk = 0; kk < 4; kk++)   // head kk's O stripe st
        ao[kk] = *(const bf16x8*)(&wreg[kk][st * 1152 + lr * QKS + lk * 8]);
#pragma unroll
      for (int nt2 = 0; nt2 < 2; nt2++) {
        f32x4 acc = zero4;
        __builtin_amdgcn_s_setprio(1);
#pragma unroll
        for (int kk = 0; kk < 4; kk++) acc = MFMA16(ao[kk], pwf[nt2][kk], acc);
        __builtin_amdgcn_s_setprio(0);
        int j = wid * 32 + nt2 * 16 + lr;
#pragma unroll
        for (int i = 0; i < 4; i++) {
          size_t off = (size_t)gidx[st][i] * 128 + j;
          out[off] = xres[st][nt2][i] + acc[i] + pb2[nt2];
        }
      }
    }
  }
}

// sigmoid-gelu: x * sigma(1.702x); |err| vs tanh-gelu < 0.005 for |x|<~1.5
__device__ __forceinline__ float gelu_sig(float x) {
  float e = exp2f(x * -2.4554826f);   // 1.702 * log2(e)
  return x * __builtin_amdgcn_rcpf(1.f + e);
}

__global__ __launch_bounds__(512, 6) void mlp_kernel(
    const float* __restrict__ ln2_w, const float* __restrict__ ln2_b,
    const float* __restrict__ mlp_b1, const float* __restrict__ mlp_b2,
    const unsigned char* __restrict__ ws, float* __restrict__ out) {
  // manual LDS layout: xn 16KB | hb 16KB | x1b 17KB = 50,176 B total.
  // epilogue reuses [0,32KB) (dead xn+hb) as the f32 staging tile.
  __shared__ __attribute__((aligned(16))) unsigned char smem[50176];
  __bf16* xn  = (__bf16*)smem;            // 64 x 128, XOR-swizzled
  __bf16* hb  = (__bf16*)(smem + 16384);  // 64 x 128 chunk, XOR-swizzled
  __bf16* x1b = (__bf16*)(smem + 32768);  // 64 x X1S bf16 stash
  const int tid = threadIdx.x;
  const int wid = tid >> 6, lane = tid & 63;
  const int lr = lane & 15, lk = lane >> 4;
  const int row0 = blockIdx.x * 64;
  const int col = wid * 16 + lr;   // this lane's output column

  const __bf16* w1r = (const __bf16*)(ws + W1_OFF);
  const __bf16* w2r = (const __bf16*)(ws + W2_OFF);

  float b2v = mlp_b2[col];

  // ---- LN2 (8 threads/row, 16 elems each) + x1 bf16 stash ----
  {
    int n = tid >> 3, q = tid & 7;
    const float4* xp = (const float4*)(out + (size_t)(row0 + n) * 128 + q * 16);
    float4 xv[4];
    float s = 0.f, s2 = 0.f;
#pragma unroll
    for (int t = 0; t < 4; t++) {
      float4 v = xp[t]; xv[t] = v;
      s += v.x + v.y + v.z + v.w;
      s2 += v.x * v.x + v.y * v.y + v.z * v.z + v.w * v.w;
    }
    s += __shfl_xor(s, 1); s += __shfl_xor(s, 2); s += __shfl_xor(s, 4);
    s2 += __shfl_xor(s2, 1); s2 += __shfl_xor(s2, 2); s2 += __shfl_xor(s2, 4);
    float mean = s * (1.f / 128.f);
    float var = s2 * (1.f / 128.f) - mean * mean;
    float rstd = rsqrtf(var + 1e-5f);
    const float4* wv = (const float4*)(ln2_w + q * 16);
    const float4* bv = (const float4*)(ln2_b + q * 16);
    bf16x8 o[2], r[2];
#pragma unroll
    for (int t = 0; t < 4; t++) {
      float4 wt = wv[t], bt = bv[t], v = xv[t];
      o[t >> 1][(t & 1) * 4 + 0] = (__bf16)((v.x - mean) * rstd * wt.x + bt.x);
      o[t >> 1][(t & 1) * 4 + 1] = (__bf16)((v.y - mean) * rstd * wt.y + bt.y);
      o[t >> 1][(t & 1) * 4 + 2] = (__bf16)((v.z - mean) * rstd * wt.z + bt.z);
      o[t >> 1][(t & 1) * 4 + 3] = (__bf16)((v.w - mean) * rstd * wt.w + bt.w);
      r[t >> 1][(t & 1) * 4 + 0] = (__bf16)v.x;
      r[t >> 1][(t & 1) * 4 + 1] = (__bf16)v.y;
      r[t >> 1][(t & 1) * 4 + 2] = (__bf16)v.z;
      r[t >> 1][(t & 1) * 4 + 3] = (__bf16)v.w;
    }
    *(bf16x8*)(xn + n * 128 + (((q * 2 + 0) ^ (n & 15)) << 3)) = o[0];
    *(bf16x8*)(xn + n * 128 + (((q * 2 + 1) ^ (n & 15)) << 3)) = o[1];
    *(bf16x8*)(x1b + n * X1S + q * 16) = r[0];
    *(bf16x8*)(x1b + n * X1S + q * 16 + 8) = r[1];
  }
  LGKM_BARRIER();

  f32x4 macc[4];
#pragma unroll
  for (int st = 0; st < 4; st++) macc[st] = (f32x4){b2v, b2v, b2v, b2v};

#pragma unroll 1
  for (int c = 0; c < 4; c++) {
    // ---- fc1 SWAPPED (C rows = hidden) + gelu -> hb[token][hidden], b64 packed ----
    {
      bf16x8 w1f[4];
#pragma unroll
      for (int kk = 0; kk < 4; kk++)
        w1f[kk] = *(const bf16x8*)(w1r + ((c * 8 + wid) * 4 + kk) * 512 + lane * 8);
      // bias per hidden row: hidden = c*128 + wid*16 + lk*4 + i -> exact f32 C-init
      f32x4 bini = *(const f32x4*)(mlp_b1 + c * 128 + wid * 16 + lk * 4);
      const int ch = wid * 2 + (lk >> 1), sub = (lk & 1) * 4;
#pragma unroll
      for (int st = 0; st < 4; st++) {
        bf16x8 a1[4];
#pragma unroll
        for (int kk = 0; kk < 4; kk++)
          a1[kk] = *(const bf16x8*)(xn + (st * 16 + lr) * 128 + (((kk * 4 + lk) ^ lr) << 3));
        f32x4 acc = bini;
#pragma unroll
        for (int kk = 0; kk < 4; kk++) acc = MFMA16(w1f[kk], a1[kk], acc);
        // lane holds 4 consecutive hidden for token st*16+lr -> single b64 store
        bf16x4 pk = {(__bf16)gelu_sig(acc[0]), (__bf16)gelu_sig(acc[1]),
                     (__bf16)gelu_sig(acc[2]), (__bf16)gelu_sig(acc[3])};
        int row = st * 16 + lr;
        *(bf16x4*)(hb + row * 128 + ((ch ^ lr) << 3) + sub) = pk;
      }
    }
    // early-issue w2f globals: latency hides under the barrier (lgkm-only drain)
    bf16x8 w2f[4];
#pragma unroll
    for (int kks = 0; kks < 4; kks++)
      w2f[kks] = *(const bf16x8*)(w2r + (wid * 16 + c * 4 + kks) * 512 + lane * 8);
    LGKM_BARRIER();

    // ---- fc2 partial over this chunk's K=128 ----
#pragma unroll
    for (int st = 0; st < 4; st++) {
#pragma unroll
      for (int kks = 0; kks < 4; kks++) {
        bf16x8 ah = *(const bf16x8*)(hb + (st * 16 + lr) * 128 + (((kks * 4 + lk) ^ lr) << 3));
        macc[st] = MFMA16(ah, w2f[kks], macc[st]);
      }
    }
    LGKM_BARRIER();  // protect hb overwrite by next fc1 / f32 staging
  }

  // ---- epilogue: stage x1(stash)+fc2+b2 (f32) over dead xn+hb, line-complete stores ----
  {
    float* stg = (float*)smem;  // 64 x 128 f32 = 32 KB (xn+hb region, both dead)
#pragma unroll
    for (int st = 0; st < 4; st++)
#pragma unroll
      for (int i = 0; i < 4; i++) {
        int row = st * 16 + lk * 4 + i;
        float x1v = (float)x1b[row * X1S + col];
        int sp = (col >> 2) ^ (((row >> 2) & 7) << 2);  // bijective slot swizzle per row
        stg[row * 128 + sp * 4 + (col & 3)] = x1v + macc[st][i];
      }
    LGKM_BARRIER();
    // each wave stores rows wid*8..wid*8+7: 1 KB contiguous per iteration,
    // every 128B line written completely by one instruction (no partial-line miss)
    int half = lane >> 5, sl = lane & 31;
#pragma unroll
    for (int it = 0; it < 4; it++) {
      int row = wid * 8 + it * 2 + half;
      int sp = sl ^ (((row >> 2) & 7) << 2);
      f32x4 v = *(const f32x4*)(stg + row * 128 + sp * 4);
      *(f32x4*)(out + (size_t)(row0 + row) * 128 + sl * 4) = v;
    }
  }
}

extern "C" void kernel_launch(void* const* d_in, const int* in_sizes, int n_in,
                              void* d_out, int out_size, void* d_ws, size_t ws_size,
                              hipStream_t stream) {
  const float* x      = (const float*)d_in[0];
  const float* ln1_w  = (const float*)d_in[1];
  const float* ln1_b  = (const float*)d_in[2];
  const float* qkv_w  = (const float*)d_in[3];
  const float* qkv_b  = (const float*)d_in[4];
  const float* rel_b  = (const float*)d_in[5];
  const float* proj_w = (const float*)d_in[6];
  const float* proj_b = (const float*)d_in[7];
  const float* ln2_w  = (const float*)d_in[8];
  const float* ln2_b  = (const float*)d_in[9];
  const float* mlp_w1 = (const float*)d_in[10];
  const float* mlp_b1 = (const float*)d_in[11];
  const float* mlp_w2 = (const float*)d_in[12];
  const float* mlp_b2 = (const float*)d_in[13];
  float* out = (float*)d_out;
  unsigned char* ws = (unsigned char*)d_ws;

  prep_kernel<<<256, 256, 0, stream>>>(qkv_w, proj_w, mlp_w1, mlp_w2, rel_b, ws);
  attn_kernel<<<4096, 256, 0, stream>>>(x, ln1_w, ln1_b, qkv_b, proj_b, ws, out);
  mlp_kernel<<<4096, 512, 0, stream>>>(ln2_w, ln2_b, mlp_b1, mlp_b2, ws, out);
}

// Round 15
// 233.480 us; speedup vs baseline: 1.5797x; 1.0059x over previous
//
#include <hip/hip_runtime.h>
#include <hip/hip_bf16.h>

// FBANetLayer: Swin-style block. H=W=512, DIM=128, WL=8, SS=4, HEADS=4, HD=32.
// attn: head-per-wave; swapped-QK^T scores with bias C-init; max-free softmax;
//       wave-private LDS; residual prefetch; raw lgkm-only barriers.
//       (setprio REVERTED: −36us on lockstep phases, m190 regime mismatch)
// mlp:  grid 4096 x 64 rows; 4 hidden chunks of 128; SWAPPED fc1 (C rows =
//       hidden) so gelu outputs pack into ds_write_b64; biases f32 C-init;
//       lgkm-only barriers; w2f issued before the post-fc1 barrier; x1 bf16
//       stash; staged line-complete stores.

typedef __bf16 bf16x8 __attribute__((ext_vector_type(8)));
typedef __bf16 bf16x4 __attribute__((ext_vector_type(4)));
typedef __bf16 bf16x2 __attribute__((ext_vector_type(2)));
typedef float f32x4 __attribute__((ext_vector_type(4)));

#define MFMA16(a, b, c) __builtin_amdgcn_mfma_f32_16x16x32_bf16(a, b, c, 0, 0, 0)
#define LGKM_BARRIER() do { \
    asm volatile("s_waitcnt lgkmcnt(0)" ::: "memory"); \
    __builtin_amdgcn_s_barrier(); } while (0)

#define SS 4
#define XS 136   // attn LDS stride (bf16) for the 128-wide xn tile (2-way banks)
#define QKS 40   // stride for 32-wide q/k/O tiles (2-way banks)
#define PSS 72   // stride for 64-wide ps / vt tiles (2-way banks)
#define X1S 136  // mlp x1-stash stride

// ws byte offsets (total 458,752 B)
#define QKV_W_OFF 0        // 384x128 bf16 frag-order: ((h*6+nt)*4+kk)*512 + lane*8
#define PROJ_W_OFF 98304   // 128x128 bf16 frag-order: ((wid*2+nt2)*4+kk)*512 + lane*8
#define W1_OFF 131072      // 512x128 bf16 frag-order, 16-row groups: (g*4+kk)*512+lane*8
#define W2_OFF 262144      // 128x512 bf16 frag-order: (wid*16+kk)*512 + lane*8
#define BIAS_OFF 393216    // bias C-frag table: f32[((h*4+qt)*4+kt)*256 + lane*4 + i]

__device__ __forceinline__ int regid(int u) { return (u >= 508) ? 2 : ((u >= 504) ? 1 : 0); }

__global__ __launch_bounds__(256) void prep_kernel(
    const float* __restrict__ qkv_w, const float* __restrict__ proj_w,
    const float* __restrict__ w1, const float* __restrict__ w2,
    const float* __restrict__ rel_bias, unsigned char* __restrict__ ws) {
  int tid = blockIdx.x * 256 + threadIdx.x;
  __bf16* qw = (__bf16*)(ws + QKV_W_OFF);
  __bf16* pw = (__bf16*)(ws + PROJ_W_OFF);
  __bf16* w1b = (__bf16*)(ws + W1_OFF);
  __bf16* w2b = (__bf16*)(ws + W2_OFF);
  float* btbl = (float*)(ws + BIAS_OFF);
  if (tid < 49152) {
    int e = tid & 7, lane = (tid >> 3) & 63, kk = (tid >> 9) & 3;
    int f = tid >> 11;            // 0..23 = h*6+nt
    int h = f / 6, nt = f % 6;
    int j = (nt >> 1) * 128 + h * 32 + (nt & 1) * 16 + (lane & 15);
    int k = kk * 32 + (lane >> 4) * 8 + e;
    qw[tid] = (__bf16)qkv_w[j * 128 + k];
  }
  if (tid < 16384) {
    int e = tid & 7, lane = (tid >> 3) & 63, kk = (tid >> 9) & 3;
    int nt2 = (tid >> 11) & 1, wid = (tid >> 12) & 3;
    int j = wid * 32 + nt2 * 16 + (lane & 15);
    int k = kk * 32 + (lane >> 4) * 8 + e;
    pw[tid] = (__bf16)proj_w[j * 128 + k];
  }
  if (tid < 65536) {
    { // w1: 32 groups of 16 rows, frag (g*4+kk); g = c*8+wid for 128-col chunks
      int e = tid & 7, lane = (tid >> 3) & 63, kk = (tid >> 9) & 3;
      int g = (tid >> 11) & 31;
      int j = g * 16 + (lane & 15);
      int k = kk * 32 + (lane >> 4) * 8 + e;
      w1b[tid] = (__bf16)w1[j * 128 + k]; }
    { // w2: plain frag-linear k order (wid*16+kk)
      int e = tid & 7, lane = (tid >> 3) & 63, kk = (tid >> 9) & 15, wid = (tid >> 13) & 7;
      int j = wid * 16 + (lane & 15);
      int k = kk * 32 + (lane >> 4) * 8 + e;
      w2b[tid] = (__bf16)w2[j * 512 + k]; }
  }
  if (tid < 16384) {
    // bias C-frag table: lane holds C[row=k-tok=(l>>4)*4+i][col=q-tok=l&15]
    int i = tid & 3, lane = (tid >> 2) & 63;
    int kt = (tid >> 8) & 3, qt = (tid >> 10) & 3, h = (tid >> 12) & 3;
    int n = qt * 16 + (lane & 15);          // q token
    int m = kt * 16 + (lane >> 4) * 4 + i;  // k token
    int idx = ((n >> 3) - (m >> 3) + 7) * 15 + ((n & 7) - (m & 7) + 7);
    btbl[tid] = rel_bias[idx * 4 + h];
  }
}

__global__ __launch_bounds__(256, 2) void attn_kernel(
    const float* __restrict__ x, const float* __restrict__ ln1_w, const float* __restrict__ ln1_b,
    const float* __restrict__ qkv_b, const float* __restrict__ proj_b,
    const unsigned char* __restrict__ ws, float* __restrict__ out) {
  __shared__ __attribute__((aligned(16))) __bf16 xn[64 * XS];   // 17,408 B
  __shared__ __attribute__((aligned(16))) __bf16 wreg[4][5120]; // 4 x 10,240 B
  __shared__ __attribute__((aligned(16))) __bf16 vt[4][32 * PSS]; // 4 x 4,608 B
  __shared__ __attribute__((aligned(16))) int rid[64];

  const int w = blockIdx.x;
  const int wi = w >> 6, wj = w & 63;
  const int tid = threadIdx.x;
  const int wid = tid >> 6, lane = tid & 63;
  const int lr = lane & 15, lk = lane >> 4;
  const bool edge = (wi == 63) || (wj == 63);
  const f32x4 zero4 = {0.f, 0.f, 0.f, 0.f};

  // ---- Hoisted QKV B-frags: wave wid's head slice {Q_h,K_h,V_h} ----
  const __bf16* qw = (const __bf16*)(ws + QKV_W_OFF);
  bf16x8 bw[6][4];
  float qb[6];
#pragma unroll
  for (int nt = 0; nt < 6; nt++) {
    qb[nt] = qkv_b[(nt >> 1) * 128 + wid * 32 + (nt & 1) * 16 + lr];
#pragma unroll
    for (int kk = 0; kk < 4; kk++)
      bw[nt][kk] = *(const bf16x8*)(qw + ((wid * 6 + nt) * 4 + kk) * 512 + lane * 8);
  }

  // ---- Phase A: gather rolled rows + LN1 -> bf16 LDS ----
  {
    int n = tid >> 2, q = tid & 3;
    int r = n >> 3, c = n & 7;
    int io = (wi * 8 + r + SS) & 511;
    int jo = (wj * 8 + c + SS) & 511;
    size_t gid = (size_t)io * 512 + jo;
    const float4* xp = (const float4*)(x + gid * 128 + q * 32);
    float4 xv[8];
    float s = 0.f, s2 = 0.f;
#pragma unroll
    for (int t = 0; t < 8; t++) {
      float4 v = xp[t]; xv[t] = v;
      s += v.x + v.y + v.z + v.w;
      s2 += v.x * v.x + v.y * v.y + v.z * v.z + v.w * v.w;
    }
    s += __shfl_xor(s, 1); s += __shfl_xor(s, 2);
    s2 += __shfl_xor(s2, 1); s2 += __shfl_xor(s2, 2);
    float mean = s * (1.f / 128.f);
    float var = s2 * (1.f / 128.f) - mean * mean;
    float rstd = rsqrtf(var + 1e-5f);
    const float4* wv = (const float4*)(ln1_w + q * 32);
    const float4* bv = (const float4*)(ln1_b + q * 32);
    __bf16* dst = xn + n * XS + q * 32;
#pragma unroll
    for (int t = 0; t < 8; t++) {
      float4 wt = wv[t], bt = bv[t], v = xv[t];
      dst[t * 4 + 0] = (__bf16)((v.x - mean) * rstd * wt.x + bt.x);
      dst[t * 4 + 1] = (__bf16)((v.y - mean) * rstd * wt.y + bt.y);
      dst[t * 4 + 2] = (__bf16)((v.z - mean) * rstd * wt.z + bt.z);
      dst[t * 4 + 3] = (__bf16)((v.w - mean) * rstd * wt.w + bt.w);
    }
    if (q == 0) rid[n] = 3 * regid(wi * 8 + r) + regid(wj * 8 + c);
  }
  LGKM_BARRIER();   // keep hoisted bw loads in flight (no vmcnt drain)

  // ---- Phase B: QKV for head wid (64 rows x 96 cols), into private LDS ----
  {
    const float scale = 0.17677669529663687f;  // 32^-0.5 folded into Q
    __bf16* qbase = &wreg[wid][0];
    __bf16* kbase = &wreg[wid][2560];
    __bf16* vbase = &vt[wid][0];
#pragma unroll
    for (int st = 0; st < 4; st++) {
      bf16x8 a[4];
#pragma unroll
      for (int kk = 0; kk < 4; kk++)
        a[kk] = *(const bf16x8*)(xn + (st * 16 + lr) * XS + kk * 32 + lk * 8);
#pragma unroll
      for (int nt = 0; nt < 6; nt++) {
        f32x4 acc = zero4;
#pragma unroll
        for (int kk = 0; kk < 4; kk++) acc = MFMA16(a[kk], bw[nt][kk], acc);
        float bias = qb[nt];
        int dl = (nt & 1) * 16 + lr;           // d_local within head
        if (nt < 2) {
#pragma unroll
          for (int i = 0; i < 4; i++)
            qbase[(st * 16 + lk * 4 + i) * QKS + dl] = (__bf16)((acc[i] + bias) * scale);
        } else if (nt < 4) {
#pragma unroll
          for (int i = 0; i < 4; i++)
            kbase[(st * 16 + lk * 4 + i) * QKS + dl] = (__bf16)(acc[i] + bias);
        } else {
#pragma unroll
          for (int i = 0; i < 4; i++)
            vbase[dl * PSS + st * 16 + lk * 4 + i] = (__bf16)(acc[i] + bias);
        }
      }
    }
  }

  // ---- hoist proj B-frags + bias C-frags (loads overlap frag staging) ----
  const __bf16* pw = (const __bf16*)(ws + PROJ_W_OFF);
  bf16x8 pwf[2][4];
  float pb2[2];
#pragma unroll
  for (int nt2 = 0; nt2 < 2; nt2++) {
    pb2[nt2] = proj_b[wid * 32 + nt2 * 16 + lr];
#pragma unroll
    for (int kk = 0; kk < 4; kk++)
      pwf[nt2][kk] = *(const bf16x8*)(pw + ((wid * 2 + nt2) * 4 + kk) * 512 + lane * 8);
  }
  const float* btbl = (const float*)(ws + BIAS_OFF);
  f32x4 bc[4][4];
#pragma unroll
  for (int qt = 0; qt < 4; qt++)
#pragma unroll
    for (int kt = 0; kt < 4; kt++)
      bc[qt][kt] = *(const f32x4*)(btbl + ((wid * 4 + qt) * 4 + kt) * 256 + lane * 4);

  // ---- prefetch residual x for phase D (latency hides under phase C) ----
  int gidx[4][4];
#pragma unroll
  for (int st = 0; st < 4; st++)
#pragma unroll
    for (int i = 0; i < 4; i++) {
      int rr = st * 16 + lk * 4 + i;
      int io = (wi * 8 + (rr >> 3) + SS) & 511;
      int jo = (wj * 8 + (rr & 7) + SS) & 511;
      gidx[st][i] = io * 512 + jo;
    }
  float xres[4][2][4];
#pragma unroll
  for (int st = 0; st < 4; st++)
#pragma unroll
    for (int nt2 = 0; nt2 < 2; nt2++)
#pragma unroll
      for (int i = 0; i < 4; i++)
        xres[st][nt2][i] = x[(size_t)gidx[st][i] * 128 + wid * 32 + nt2 * 16 + lr];

  // ---- Phase C: head-private attention (no barriers) ----
  {
    __bf16* reg0 = &wreg[wid][0];
    bf16x8 kf[4], qf[4], vf[2][2];
#pragma unroll
    for (int kt = 0; kt < 4; kt++)
      kf[kt] = *(const bf16x8*)(reg0 + 2560 + (kt * 16 + lr) * QKS + lk * 8);
#pragma unroll
    for (int qt = 0; qt < 4; qt++)
      qf[qt] = *(const bf16x8*)(reg0 + (qt * 16 + lr) * QKS + lk * 8);
#pragma unroll
    for (int dt = 0; dt < 2; dt++)
#pragma unroll
      for (int kk = 0; kk < 2; kk++)
        vf[dt][kk] = *(const bf16x8*)(&vt[wid][(dt * 16 + lr) * PSS + kk * 32 + lk * 8]);
    // ensure frag reads retired before overwriting region with ps
    asm volatile("s_waitcnt lgkmcnt(0)" ::: "memory");
    __builtin_amdgcn_sched_barrier(0);

    int4 rk[4];
    if (edge) {
#pragma unroll
      for (int kt = 0; kt < 4; kt++) rk[kt] = *(const int4*)&rid[kt * 16 + lk * 4];
    }

#pragma unroll
    for (int qt = 0; qt < 4; qt++) {
      f32x4 s[4];
#pragma unroll
      for (int kt = 0; kt < 4; kt++) s[kt] = MFMA16(kf[kt], qf[qt], bc[qt][kt]);
      if (edge) {
        int rq = rid[qt * 16 + lr];
#pragma unroll
        for (int kt = 0; kt < 4; kt++) {
          s[kt][0] += (rk[kt].x != rq) ? -100.f : 0.f;
          s[kt][1] += (rk[kt].y != rq) ? -100.f : 0.f;
          s[kt][2] += (rk[kt].z != rq) ? -100.f : 0.f;
          s[kt][3] += (rk[kt].w != rq) ? -100.f : 0.f;
        }
      }
      float ex[4][4];
      float sum = 0.f;
#pragma unroll
      for (int kt = 0; kt < 4; kt++) {
#pragma unroll
        for (int i = 0; i < 4; i++) { ex[kt][i] = __expf(s[kt][i]); sum += ex[kt][i]; }
      }
      sum += __shfl_xor(sum, 16);
      sum += __shfl_xor(sum, 32);
      float inv = __builtin_amdgcn_rcpf(sum);
      __bf16* psrow = reg0 + (qt * 16 + lr) * PSS;
#pragma unroll
      for (int kt = 0; kt < 4; kt++) {
        bf16x2 p01 = {(__bf16)(ex[kt][0] * inv), (__bf16)(ex[kt][1] * inv)};
        bf16x2 p23 = {(__bf16)(ex[kt][2] * inv), (__bf16)(ex[kt][3] * inv)};
        *(bf16x2*)(psrow + kt * 16 + lk * 4) = p01;
        *(bf16x2*)(psrow + kt * 16 + lk * 4 + 2) = p23;
      }
#pragma unroll
      for (int dt = 0; dt < 2; dt++) {
        bf16x8 pa0 = *(const bf16x8*)(reg0 + (qt * 16 + lr) * PSS + lk * 8);
        bf16x8 pa1 = *(const bf16x8*)(reg0 + (qt * 16 + lr) * PSS + 32 + lk * 8);
        f32x4 acc = MFMA16(pa0, vf[dt][0], zero4);
        acc = MFMA16(pa1, vf[dt][1], acc);
#pragma unroll
        for (int i = 0; i < 4; i++)
          reg0[qt * 1152 + (lk * 4 + i) * QKS + dt * 16 + lr] = (__bf16)acc[i];
      }
    }
  }
  LGKM_BARRIER();   // keep xres prefetch in flight (no vmcnt drain)

  // ---- Phase D: proj col-slice (wave owns 32 cols) + residual, inverse roll ----
  {
#pragma unroll
    for (int st = 0; st < 4; st++) {
      bf16x8 ao[4];
#pragma unroll
      for (int kk = 0; kk < 4; kk++)   // head kk's O stripe st
        ao[kk] = *(const bf16x8*)(&wreg[kk][st * 1152 + lr * QKS + lk * 8]);
#pragma unroll
      for (int nt2 = 0; nt2 < 2; nt2++) {
        f32x4 acc = zero4;
#pragma unroll
        for (int kk = 0; kk < 4; kk++) acc = MFMA16(ao[kk], pwf[nt2][kk], acc);
        int j = wid * 32 + nt2 * 16 + lr;
#pragma unroll
        for (int i = 0; i < 4; i++) {
          size_t off = (size_t)gidx[st][i] * 128 + j;
          out[off] = xres[st][nt2][i] + acc[i] + pb2[nt2];
        }
      }
    }
  }
}

// sigmoid-gelu: x * sigma(1.702x); |err| vs tanh-gelu < 0.005 for |x|<~1.5
__device__ __forceinline__ float gelu_sig(float x) {
  float e = exp2f(x * -2.4554826f);   // 1.702 * log2(e)
  return x * __builtin_amdgcn_rcpf(1.f + e);
}

__global__ __launch_bounds__(512, 6) void mlp_kernel(
    const float* __restrict__ ln2_w, const float* __restrict__ ln2_b,
    const float* __restrict__ mlp_b1, const float* __restrict__ mlp_b2,
    const unsigned char* __restrict__ ws, float* __restrict__ out) {
  // manual LDS layout: xn 16KB | hb 16KB | x1b 17KB = 50,176 B total.
  // epilogue reuses [0,32KB) (dead xn+hb) as the f32 staging tile.
  __shared__ __attribute__((aligned(16))) unsigned char smem[50176];
  __bf16* xn  = (__bf16*)smem;            // 64 x 128, XOR-swizzled
  __bf16* hb  = (__bf16*)(smem + 16384);  // 64 x 128 chunk, XOR-swizzled
  __bf16* x1b = (__bf16*)(smem + 32768);  // 64 x X1S bf16 stash
  const int tid = threadIdx.x;
  const int wid = tid >> 6, lane = tid & 63;
  const int lr = lane & 15, lk = lane >> 4;
  const int row0 = blockIdx.x * 64;
  const int col = wid * 16 + lr;   // this lane's output column

  const __bf16* w1r = (const __bf16*)(ws + W1_OFF);
  const __bf16* w2r = (const __bf16*)(ws + W2_OFF);

  float b2v = mlp_b2[col];

  // ---- LN2 (8 threads/row, 16 elems each) + x1 bf16 stash ----
  {
    int n = tid >> 3, q = tid & 7;
    const float4* xp = (const float4*)(out + (size_t)(row0 + n) * 128 + q * 16);
    float4 xv[4];
    float s = 0.f, s2 = 0.f;
#pragma unroll
    for (int t = 0; t < 4; t++) {
      float4 v = xp[t]; xv[t] = v;
      s += v.x + v.y + v.z + v.w;
      s2 += v.x * v.x + v.y * v.y + v.z * v.z + v.w * v.w;
    }
    s += __shfl_xor(s, 1); s += __shfl_xor(s, 2); s += __shfl_xor(s, 4);
    s2 += __shfl_xor(s2, 1); s2 += __shfl_xor(s2, 2); s2 += __shfl_xor(s2, 4);
    float mean = s * (1.f / 128.f);
    float var = s2 * (1.f / 128.f) - mean * mean;
    float rstd = rsqrtf(var + 1e-5f);
    const float4* wv = (const float4*)(ln2_w + q * 16);
    const float4* bv = (const float4*)(ln2_b + q * 16);
    bf16x8 o[2], r[2];
#pragma unroll
    for (int t = 0; t < 4; t++) {
      float4 wt = wv[t], bt = bv[t], v = xv[t];
      o[t >> 1][(t & 1) * 4 + 0] = (__bf16)((v.x - mean) * rstd * wt.x + bt.x);
      o[t >> 1][(t & 1) * 4 + 1] = (__bf16)((v.y - mean) * rstd * wt.y + bt.y);
      o[t >> 1][(t & 1) * 4 + 2] = (__bf16)((v.z - mean) * rstd * wt.z + bt.z);
      o[t >> 1][(t & 1) * 4 + 3] = (__bf16)((v.w - mean) * rstd * wt.w + bt.w);
      r[t >> 1][(t & 1) * 4 + 0] = (__bf16)v.x;
      r[t >> 1][(t & 1) * 4 + 1] = (__bf16)v.y;
      r[t >> 1][(t & 1) * 4 + 2] = (__bf16)v.z;
      r[t >> 1][(t & 1) * 4 + 3] = (__bf16)v.w;
    }
    *(bf16x8*)(xn + n * 128 + (((q * 2 + 0) ^ (n & 15)) << 3)) = o[0];
    *(bf16x8*)(xn + n * 128 + (((q * 2 + 1) ^ (n & 15)) << 3)) = o[1];
    *(bf16x8*)(x1b + n * X1S + q * 16) = r[0];
    *(bf16x8*)(x1b + n * X1S + q * 16 + 8) = r[1];
  }
  LGKM_BARRIER();

  f32x4 macc[4];
#pragma unroll
  for (int st = 0; st < 4; st++) macc[st] = (f32x4){b2v, b2v, b2v, b2v};

#pragma unroll 1
  for (int c = 0; c < 4; c++) {
    // ---- fc1 SWAPPED (C rows = hidden) + gelu -> hb[token][hidden], b64 packed ----
    {
      bf16x8 w1f[4];
#pragma unroll
      for (int kk = 0; kk < 4; kk++)
        w1f[kk] = *(const bf16x8*)(w1r + ((c * 8 + wid) * 4 + kk) * 512 + lane * 8);
      // bias per hidden row: hidden = c*128 + wid*16 + lk*4 + i -> exact f32 C-init
      f32x4 bini = *(const f32x4*)(mlp_b1 + c * 128 + wid * 16 + lk * 4);
      const int ch = wid * 2 + (lk >> 1), sub = (lk & 1) * 4;
#pragma unroll
      for (int st = 0; st < 4; st++) {
        bf16x8 a1[4];
#pragma unroll
        for (int kk = 0; kk < 4; kk++)
          a1[kk] = *(const bf16x8*)(xn + (st * 16 + lr) * 128 + (((kk * 4 + lk) ^ lr) << 3));
        f32x4 acc = bini;
#pragma unroll
        for (int kk = 0; kk < 4; kk++) acc = MFMA16(w1f[kk], a1[kk], acc);
        // lane holds 4 consecutive hidden for token st*16+lr -> single b64 store
        bf16x4 pk = {(__bf16)gelu_sig(acc[0]), (__bf16)gelu_sig(acc[1]),
                     (__bf16)gelu_sig(acc[2]), (__bf16)gelu_sig(acc[3])};
        int row = st * 16 + lr;
        *(bf16x4*)(hb + row * 128 + ((ch ^ lr) << 3) + sub) = pk;
      }
    }
    // early-issue w2f globals: latency hides under the barrier (lgkm-only drain)
    bf16x8 w2f[4];
#pragma unroll
    for (int kks = 0; kks < 4; kks++)
      w2f[kks] = *(const bf16x8*)(w2r + (wid * 16 + c * 4 + kks) * 512 + lane * 8);
    LGKM_BARRIER();

    // ---- fc2 partial over this chunk's K=128 ----
#pragma unroll
    for (int st = 0; st < 4; st++) {
#pragma unroll
      for (int kks = 0; kks < 4; kks++) {
        bf16x8 ah = *(const bf16x8*)(hb + (st * 16 + lr) * 128 + (((kks * 4 + lk) ^ lr) << 3));
        macc[st] = MFMA16(ah, w2f[kks], macc[st]);
      }
    }
    LGKM_BARRIER();  // protect hb overwrite by next fc1 / f32 staging
  }

  // ---- epilogue: stage x1(stash)+fc2+b2 (f32) over dead xn+hb, line-complete stores ----
  {
    float* stg = (float*)smem;  // 64 x 128 f32 = 32 KB (xn+hb region, both dead)
#pragma unroll
    for (int st = 0; st < 4; st++)
#pragma unroll
      for (int i = 0; i < 4; i++) {
        int row = st * 16 + lk * 4 + i;
        float x1v = (float)x1b[row * X1S + col];
        int sp = (col >> 2) ^ (((row >> 2) & 7) << 2);  // bijective slot swizzle per row
        stg[row * 128 + sp * 4 + (col & 3)] = x1v + macc[st][i];
      }
    LGKM_BARRIER();
    // each wave stores rows wid*8..wid*8+7: 1 KB contiguous per iteration,
    // every 128B line written completely by one instruction (no partial-line miss)
    int half = lane >> 5, sl = lane & 31;
#pragma unroll
    for (int it = 0; it < 4; it++) {
      int row = wid * 8 + it * 2 + half;
      int sp = sl ^ (((row >> 2) & 7) << 2);
      f32x4 v = *(const f32x4*)(stg + row * 128 + sp * 4);
      *(f32x4*)(out + (size_t)(row0 + row) * 128 + sl * 4) = v;
    }
  }
}

extern "C" void kernel_launch(void* const* d_in, const int* in_sizes, int n_in,
                              void* d_out, int out_size, void* d_ws, size_t ws_size,
                              hipStream_t stream) {
  const float* x      = (const float*)d_in[0];
  const float* ln1_w  = (const float*)d_in[1];
  const float* ln1_b  = (const float*)d_in[2];
  const float* qkv_w  = (const float*)d_in[3];
  const float* qkv_b  = (const float*)d_in[4];
  const float* rel_b  = (const float*)d_in[5];
  const float* proj_w = (const float*)d_in[6];
  const float* proj_b = (const float*)d_in[7];
  const float* ln2_w  = (const float*)d_in[8];
  const float* ln2_b  = (const float*)d_in[9];
  const float* mlp_w1 = (const float*)d_in[10];
  const float* mlp_b1 = (const float*)d_in[11];
  const float* mlp_w2 = (const float*)d_in[12];
  const float* mlp_b2 = (const float*)d_in[13];
  float* out = (float*)d_out;
  unsigned char* ws = (unsigned char*)d_ws;

  prep_kernel<<<256, 256, 0, stream>>>(qkv_w, proj_w, mlp_w1, mlp_w2, rel_b, ws);
  attn_kernel<<<4096, 256, 0, stream>>>(x, ln1_w, ln1_b, qkv_b, proj_b, ws, out);
  mlp_kernel<<<4096, 512, 0, stream>>>(ln2_w, ln2_b, mlp_b1, mlp_b2, ws, out);
}